// Round 4
// baseline (894.572 us; speedup 1.0000x reference)
//
#include <hip/hip_runtime.h>
#include <cstddef>

constexpr int N_ = 65536;
constexpr int K_ = 16;
constexpr int E_ = N_ * K_;      // 1048576
constexpr int C_ = 64;
#define EPS_ 1e-5f

// ---------------------------------------------------------------------------
// BN stats reducer (R2 fix: parallel, 4x unrolled, LDS tree; ~<5us).
__global__ __launch_bounds__(1024)
void k_reduce_bn(const float* __restrict__ part, int P, int nchp, int nch,
                 float invM, const float* __restrict__ g,
                 const float* __restrict__ b, float* __restrict__ ss)
{
    int t = threadIdx.x;
    int c = t & (nchp - 1);
    int r = t / nchp;             // 0..R-1
    int R = 1024 / nchp;
    int stride = 2 * nchp;
    float s0 = 0.f, s1 = 0.f, s2 = 0.f, s3 = 0.f;
    float q0 = 0.f, q1 = 0.f, q2 = 0.f, q3 = 0.f;
    int p = r;
    for (; p + 3 * R < P; p += 4 * R) {
        int i0 = p * stride + c;
        int i1 = (p + R) * stride + c;
        int i2 = (p + 2 * R) * stride + c;
        int i3 = (p + 3 * R) * stride + c;
        s0 += part[i0];        s1 += part[i1];
        s2 += part[i2];        s3 += part[i3];
        q0 += part[i0 + nchp]; q1 += part[i1 + nchp];
        q2 += part[i2 + nchp]; q3 += part[i3 + nchp];
    }
    for (; p < P; p += R) {
        s0 += part[p * stride + c];
        q0 += part[p * stride + nchp + c];
    }
    float s = (s0 + s1) + (s2 + s3);
    float q = (q0 + q1) + (q2 + q3);
    __shared__ float reds[1024], redq[1024];
    reds[t] = s; redq[t] = q;
    __syncthreads();
    for (int off = 512; off >= nchp; off >>= 1) {
        if (t < off) { reds[t] += reds[t + off]; redq[t] += redq[t + off]; }
        __syncthreads();
    }
    if (t < nch) {
        float mean = reds[t] * invM;
        float var  = fmaxf(redq[t] * invM - mean * mean, 0.f);
        float sc = g[t] * rsqrtf(var + EPS_);
        ss[t] = sc;
        ss[nchp + t] = b[t] - mean * sc;
    }
}

// ---------------------------------------------------------------------------
// Column stats over [65536 x 64] row-major buffer. Grid 256 blocks x 256 thr.
__global__ __launch_bounds__(256)
void k_colstats(const float* __restrict__ buf, float* __restrict__ part)
{
    int t = threadIdx.x, c = t & 63, rg = t >> 6;
    float s = 0.f, q = 0.f;
    int base = blockIdx.x * 256 + rg * 64;
    for (int i = 0; i < 64; ++i) {
        float v = buf[(size_t)(base + i) * 64 + c];
        s += v; q = fmaf(v, v, q);
    }
    __shared__ float red[2][256];
    red[0][t] = s; red[1][t] = q;
    __syncthreads();
    if (t < 64) {
        float S = red[0][t] + red[0][t + 64] + red[0][t + 128] + red[0][t + 192];
        float Q = red[1][t] + red[1][t + 64] + red[1][t + 128] + red[1][t + 192];
        part[blockIdx.x * 128 + t]      = S;
        part[blockIdx.x * 128 + 64 + t] = Q;
    }
}

// ---------------------------------------------------------------------------
// R3 post-mortem: old thread-per-row GEMM scattered 16B stores at stride 256B
// -> 4.6x HBM write amplification (WRITE_SIZE 220MB vs 48MB real), 1.27 TB/s,
// 184us. New structure: 2 threads/row (wave-split ch halves so W loads stay
// wave-uniform scalar), accumulate -> LDS tile -> cooperative coalesced
// write-out (1KB per wave-store). 512 blocks x 256 thr, 128 rows/block.

// Compute 32 channels of one row into acc[8] (ch0 wave-uniform).
__device__ __forceinline__ void gemm_half_row(const float xr[64],
                                              const float* __restrict__ W,
                                              const float* __restrict__ bias,
                                              int ch0, float4 acc[8])
{
#pragma unroll
    for (int c4 = 0; c4 < 8; ++c4) {
        int cb = ch0 + 4 * c4;
        float4 a;
        a.x = bias ? bias[cb + 0] : 0.f;
        a.y = bias ? bias[cb + 1] : 0.f;
        a.z = bias ? bias[cb + 2] : 0.f;
        a.w = bias ? bias[cb + 3] : 0.f;
#pragma unroll
        for (int k = 0; k < 64; ++k) {
            float xv = xr[k];
            a.x = fmaf(xv, W[(cb + 0) * 64 + k], a.x);
            a.y = fmaf(xv, W[(cb + 1) * 64 + k], a.y);
            a.z = fmaf(xv, W[(cb + 2) * 64 + k], a.z);
            a.w = fmaf(xv, W[(cb + 3) * 64 + k], a.w);
        }
        acc[c4] = a;
    }
}

#define LDS_STRIDE 68   // mult-of-4 (float4 align), breaks pow2 bank pattern

__device__ __forceinline__ void store_tile(float* __restrict__ lds, int t, int rloc,
                                           int ch0, const float4 acc[8], int row0,
                                           float* __restrict__ om)
{
#pragma unroll
    for (int c4 = 0; c4 < 8; ++c4)
        *(float4*)&lds[rloc * LDS_STRIDE + ch0 + 4 * c4] = acc[c4];
    __syncthreads();
#pragma unroll
    for (int it = 0; it < 8; ++it) {
        int m = t + 256 * it;           // 0..2047 = 128 rows x 16 chunks
        int r = m >> 4, c4 = m & 15;
        float4 v = *(const float4*)&lds[r * LDS_STRIDE + 4 * c4];
        ((float4*)om)[(size_t)(row0 + r) * 16 + c4] = v;
    }
    __syncthreads();
}

// y = (optional relu(bn(in))) @ W^T (+bias), coalesced writes.
__global__ __launch_bounds__(256)
void k_gemm1_v2(const float* __restrict__ in, const float* __restrict__ W,
                const float* __restrict__ bias, const float* __restrict__ ss,
                float* __restrict__ out)
{
    __shared__ float lds[128 * LDS_STRIDE];
    int t = threadIdx.x;
    int rloc = (t & 63) + 64 * (t >> 7);                    // 0..127
    int ch0 = __builtin_amdgcn_readfirstlane(32 * ((t >> 6) & 1));
    int row0 = blockIdx.x * 128;
    int n = row0 + rloc;
    float xr[64];
    const float4* inr = (const float4*)(in + (size_t)n * 64);
#pragma unroll
    for (int i = 0; i < 16; ++i) {
        float4 v = inr[i];
        xr[4 * i + 0] = v.x; xr[4 * i + 1] = v.y;
        xr[4 * i + 2] = v.z; xr[4 * i + 3] = v.w;
    }
    if (ss) {
#pragma unroll
        for (int k = 0; k < 64; ++k)
            xr[k] = fmaxf(fmaf(xr[k], ss[k], ss[64 + k]), 0.f);
    }
    float4 acc[8];
    gemm_half_row(xr, W, bias, ch0, acc);
    store_tile(lds, t, rloc, ch0, acc, row0, out);
}

// h = relu(bn1(y)); a_src = h@Wa^T+ba; a_dst = h@Wb^T+bb; hW = h@Wc^T+bc
__global__ __launch_bounds__(256)
void k_gemm3_v2(const float* __restrict__ y, const float* __restrict__ ss,
                const float* __restrict__ Wa, const float* __restrict__ ba,
                const float* __restrict__ Wb, const float* __restrict__ bb,
                const float* __restrict__ Wc, const float* __restrict__ bc,
                float* __restrict__ oa, float* __restrict__ ob, float* __restrict__ oc)
{
    __shared__ float lds[128 * LDS_STRIDE];
    int t = threadIdx.x;
    int rloc = (t & 63) + 64 * (t >> 7);
    int ch0 = __builtin_amdgcn_readfirstlane(32 * ((t >> 6) & 1));
    int row0 = blockIdx.x * 128;
    int n = row0 + rloc;
    float xr[64];
    const float4* inr = (const float4*)(y + (size_t)n * 64);
#pragma unroll
    for (int i = 0; i < 16; ++i) {
        float4 v = inr[i];
        xr[4 * i + 0] = v.x; xr[4 * i + 1] = v.y;
        xr[4 * i + 2] = v.z; xr[4 * i + 3] = v.w;
    }
#pragma unroll
    for (int k = 0; k < 64; ++k)
        xr[k] = fmaxf(fmaf(xr[k], ss[k], ss[64 + k]), 0.f);
    float4 acc[8];
    gemm_half_row(xr, Wa, ba, ch0, acc);
    store_tile(lds, t, rloc, ch0, acc, row0, oa);
    gemm_half_row(xr, Wb, bb, ch0, acc);
    store_tile(lds, t, rloc, ch0, acc, row0, ob);
    gemm_half_row(xr, Wc, bc, ch0, acc);
    store_tile(lds, t, rloc, ch0, acc, row0, oc);
}

// ---------------------------------------------------------------------------
// d-vector (pos_nn hidden after BN+ReLU) for one edge. All weights uniform.
__device__ __forceinline__ void compute_d(const float* __restrict__ pos, int si, int di,
                                          const float* __restrict__ pw1,
                                          const float* __restrict__ pb1,
                                          const float* __restrict__ sspos,
                                          float& d0, float& d1, float& d2)
{
    float rx = pos[3 * si + 0] - pos[3 * di + 0];
    float ry = pos[3 * si + 1] - pos[3 * di + 1];
    float rz = pos[3 * si + 2] - pos[3 * di + 2];
    float u0 = fmaf(rx, pw1[0], fmaf(ry, pw1[1], fmaf(rz, pw1[2], pb1[0])));
    float u1 = fmaf(rx, pw1[3], fmaf(ry, pw1[4], fmaf(rz, pw1[5], pb1[1])));
    float u2 = fmaf(rx, pw1[6], fmaf(ry, pw1[7], fmaf(rz, pw1[8], pb1[2])));
    d0 = fmaxf(fmaf(u0, sspos[0], sspos[4]), 0.f);
    d1 = fmaxf(fmaf(u1, sspos[1], sspos[5]), 0.f);
    d2 = fmaxf(fmaf(u2, sspos[2], sspos[6]), 0.f);
}

// ---------------------------------------------------------------------------
// Stats of u = rel @ pos_w1^T + pos_b1 over E edges (3 channels, pad 4).
__global__ __launch_bounds__(256)
void k_pos_stats(const float* __restrict__ pos, const int* __restrict__ src,
                 const float* __restrict__ pw1, const float* __restrict__ pb1,
                 float* __restrict__ part)
{
    float s0 = 0, s1 = 0, s2 = 0, q0 = 0, q1 = 0, q2 = 0;
    int tid = blockIdx.x * 256 + threadIdx.x;
    for (int e = tid; e < E_; e += 1024 * 256) {
        int si = src[e], di = e >> 4;
        float rx = pos[3 * si + 0] - pos[3 * di + 0];
        float ry = pos[3 * si + 1] - pos[3 * di + 1];
        float rz = pos[3 * si + 2] - pos[3 * di + 2];
        float u0 = fmaf(rx, pw1[0], fmaf(ry, pw1[1], fmaf(rz, pw1[2], pb1[0])));
        float u1 = fmaf(rx, pw1[3], fmaf(ry, pw1[4], fmaf(rz, pw1[5], pb1[1])));
        float u2 = fmaf(rx, pw1[6], fmaf(ry, pw1[7], fmaf(rz, pw1[8], pb1[2])));
        s0 += u0; q0 = fmaf(u0, u0, q0);
        s1 += u1; q1 = fmaf(u1, u1, q1);
        s2 += u2; q2 = fmaf(u2, u2, q2);
    }
#pragma unroll
    for (int m = 1; m < 64; m <<= 1) {
        s0 += __shfl_xor(s0, m, 64); s1 += __shfl_xor(s1, m, 64); s2 += __shfl_xor(s2, m, 64);
        q0 += __shfl_xor(q0, m, 64); q1 += __shfl_xor(q1, m, 64); q2 += __shfl_xor(q2, m, 64);
    }
    __shared__ float red[4][8];
    int wv = threadIdx.x >> 6, ln = threadIdx.x & 63;
    if (ln == 0) {
        red[wv][0] = s0; red[wv][1] = s1; red[wv][2] = s2; red[wv][3] = 0.f;
        red[wv][4] = q0; red[wv][5] = q1; red[wv][6] = q2; red[wv][7] = 0.f;
    }
    __syncthreads();
    if (threadIdx.x < 8)
        part[blockIdx.x * 8 + threadIdx.x] =
            red[0][threadIdx.x] + red[1][threadIdx.x] + red[2][threadIdx.x] + red[3][threadIdx.x];
}

// ---------------------------------------------------------------------------
// Stats of a = a_src[src] - a_dst[dst] + delta over E edges (64 channels).
__global__ __launch_bounds__(256)
void k_abn1_stats(const float* __restrict__ pos, const int* __restrict__ src,
                  const float* __restrict__ asrc, const float* __restrict__ adst,
                  const float* __restrict__ pw1, const float* __restrict__ pb1,
                  const float* __restrict__ sspos, const float* __restrict__ pw2,
                  const float* __restrict__ pb2, float* __restrict__ part)
{
    float sacc[64], qacc[64];
#pragma unroll
    for (int i = 0; i < 64; ++i) { sacc[i] = 0.f; qacc[i] = 0.f; }
    int tid = blockIdx.x * 256 + threadIdx.x;
    for (int e = tid; e < E_; e += 1024 * 256) {
        int si = src[e], di = e >> 4;
        float d0, d1, d2;
        compute_d(pos, si, di, pw1, pb1, sspos, d0, d1, d2);
        const float4* ar = (const float4*)(asrc + (size_t)si * 64);
        const float4* dr = (const float4*)(adst + (size_t)di * 64);
#pragma unroll
        for (int c4 = 0; c4 < 16; ++c4) {
            float4 av = ar[c4], dv = dr[c4];
            int c = 4 * c4;
#define PROCA(comp, cc) { \
            float del = fmaf(d0, pw2[3*(cc)+0], fmaf(d1, pw2[3*(cc)+1], fmaf(d2, pw2[3*(cc)+2], pb2[(cc)]))); \
            float a = av.comp - dv.comp + del; \
            sacc[(cc)] += a; qacc[(cc)] = fmaf(a, a, qacc[(cc)]); }
            PROCA(x, c + 0) PROCA(y, c + 1) PROCA(z, c + 2) PROCA(w, c + 3)
#undef PROCA
        }
    }
#pragma unroll
    for (int c = 0; c < 64; ++c) {
        float s = sacc[c], q = qacc[c];
#pragma unroll
        for (int m = 1; m < 64; m <<= 1) { s += __shfl_xor(s, m, 64); q += __shfl_xor(q, m, 64); }
        sacc[c] = s; qacc[c] = q;
    }
    __shared__ float red[4][128];
    int wv = threadIdx.x >> 6, ln = threadIdx.x & 63;
    if (ln == 0) {
#pragma unroll
        for (int c = 0; c < 64; ++c) { red[wv][c] = sacc[c]; red[wv][64 + c] = qacc[c]; }
    }
    __syncthreads();
    if (threadIdx.x < 128)
        part[blockIdx.x * 128 + threadIdx.x] =
            red[0][threadIdx.x] + red[1][threadIdx.x] + red[2][threadIdx.x] + red[3][threadIdx.x];
}

// ---------------------------------------------------------------------------
// t1 = relu(abn1(a)) @ attn_w1^T + attn_b1  [E,8]; also abn2 stats (8 ch).
__global__ __launch_bounds__(256)
void k_edge_t1(const float* __restrict__ pos, const int* __restrict__ src,
               const float* __restrict__ asrc, const float* __restrict__ adst,
               const float* __restrict__ pw1, const float* __restrict__ pb1,
               const float* __restrict__ sspos, const float* __restrict__ pw2,
               const float* __restrict__ pb2, const float* __restrict__ ssa1,
               const float* __restrict__ aw1, const float* __restrict__ ab1,
               float* __restrict__ t1, float* __restrict__ part)
{
    float ssum[8], sq[8];
#pragma unroll
    for (int j = 0; j < 8; ++j) { ssum[j] = 0.f; sq[j] = 0.f; }
    int tid = blockIdx.x * 256 + threadIdx.x;
    for (int e = tid; e < E_; e += 1024 * 256) {
        int si = src[e], di = e >> 4;
        float d0, d1, d2;
        compute_d(pos, si, di, pw1, pb1, sspos, d0, d1, d2);
        const float4* ar = (const float4*)(asrc + (size_t)si * 64);
        const float4* dr = (const float4*)(adst + (size_t)di * 64);
        float tp[8];
#pragma unroll
        for (int j = 0; j < 8; ++j) tp[j] = ab1[j];
#pragma unroll
        for (int c4 = 0; c4 < 16; ++c4) {
            float4 av = ar[c4], dv = dr[c4];
            int c = 4 * c4;
#define PROCB(comp, cc) { \
            float del = fmaf(d0, pw2[3*(cc)+0], fmaf(d1, pw2[3*(cc)+1], fmaf(d2, pw2[3*(cc)+2], pb2[(cc)]))); \
            float a = av.comp - dv.comp + del; \
            float an = fmaxf(fmaf(a, ssa1[(cc)], ssa1[64 + (cc)]), 0.f); \
            _Pragma("unroll") \
            for (int j = 0; j < 8; ++j) tp[j] = fmaf(an, aw1[j * 64 + (cc)], tp[j]); }
            PROCB(x, c + 0) PROCB(y, c + 1) PROCB(z, c + 2) PROCB(w, c + 3)
#undef PROCB
        }
        float4 o0 = {tp[0], tp[1], tp[2], tp[3]};
        float4 o1 = {tp[4], tp[5], tp[6], tp[7]};
        float4* t4 = (float4*)(t1 + (size_t)e * 8);
        t4[0] = o0; t4[1] = o1;
#pragma unroll
        for (int j = 0; j < 8; ++j) { ssum[j] += tp[j]; sq[j] = fmaf(tp[j], tp[j], sq[j]); }
    }
#pragma unroll
    for (int j = 0; j < 8; ++j) {
        float s = ssum[j], q = sq[j];
#pragma unroll
        for (int m = 1; m < 64; m <<= 1) { s += __shfl_xor(s, m, 64); q += __shfl_xor(q, m, 64); }
        ssum[j] = s; sq[j] = q;
    }
    __shared__ float red[4][16];
    int wv = threadIdx.x >> 6, ln = threadIdx.x & 63;
    if (ln == 0) {
#pragma unroll
        for (int j = 0; j < 8; ++j) { red[wv][j] = ssum[j]; red[wv][8 + j] = sq[j]; }
    }
    __syncthreads();
    if (threadIdx.x < 16)
        part[blockIdx.x * 16 + threadIdx.x] =
            red[0][threadIdx.x] + red[1][threadIdx.x] + red[2][threadIdx.x] + red[3][threadIdx.x];
}

// ---------------------------------------------------------------------------
// Final edge pass: softmax over each node's 16 contiguous edges + aggregate.
__global__ __launch_bounds__(256)
void k_node_aggr(const float* __restrict__ pos, const int* __restrict__ src,
                 const float* __restrict__ t1, const float* __restrict__ ssa2,
                 const float* __restrict__ aw2, const float* __restrict__ ab2,
                 const float* __restrict__ hw, const float* __restrict__ sspos,
                 const float* __restrict__ pw1, const float* __restrict__ pb1,
                 const float* __restrict__ pw2, const float* __restrict__ pb2,
                 float* __restrict__ out)
{
    int t = threadIdx.x;
    int e = blockIdx.x * 256 + t;
    int n = e >> 4;
    int k = t & 15;
    const float4* t4 = (const float4*)(t1 + (size_t)e * 8);
    float4 ta = t4[0], tb = t4[1];
    float tv[8] = {ta.x, ta.y, ta.z, ta.w, tb.x, tb.y, tb.z, tb.w};
    float tn[8];
#pragma unroll
    for (int j = 0; j < 8; ++j) tn[j] = fmaxf(fmaf(tv[j], ssa2[j], ssa2[8 + j]), 0.f);
    float al[8];
#pragma unroll
    for (int j = 0; j < 8; ++j) {
        float acc = ab2[j];
#pragma unroll
        for (int i = 0; i < 8; ++i) acc = fmaf(tn[i], aw2[j * 8 + i], acc);
        float m = acc;
#pragma unroll
        for (int msk = 1; msk < 16; msk <<= 1) m = fmaxf(m, __shfl_xor(m, msk, 64));
        float ex = __expf(acc - m);
        float sm = ex;
#pragma unroll
        for (int msk = 1; msk < 16; msk <<= 1) sm += __shfl_xor(sm, msk, 64);
        al[j] = ex / sm;
    }
    int si = src[e];
    float d0, d1, d2;
    compute_d(pos, si, n, pw1, pb1, sspos, d0, d1, d2);
    const float4* hr = (const float4*)(hw + (size_t)si * 64);
    float4 keep = {0.f, 0.f, 0.f, 0.f};
#pragma unroll
    for (int c4 = 0; c4 < 16; ++c4) {
        float4 hv = hr[c4];
        int c = 4 * c4;
        float m0 = (hv.x + fmaf(d0, pw2[3*c+0], fmaf(d1, pw2[3*c+1],  fmaf(d2, pw2[3*c+2],  pb2[c+0])))) * al[(c+0)&7];
        float m1 = (hv.y + fmaf(d0, pw2[3*c+3], fmaf(d1, pw2[3*c+4],  fmaf(d2, pw2[3*c+5],  pb2[c+1])))) * al[(c+1)&7];
        float m2 = (hv.z + fmaf(d0, pw2[3*c+6], fmaf(d1, pw2[3*c+7],  fmaf(d2, pw2[3*c+8],  pb2[c+2])))) * al[(c+2)&7];
        float m3 = (hv.w + fmaf(d0, pw2[3*c+9], fmaf(d1, pw2[3*c+10], fmaf(d2, pw2[3*c+11], pb2[c+3])))) * al[(c+3)&7];
#pragma unroll
        for (int msk = 1; msk < 16; msk <<= 1) {
            m0 += __shfl_xor(m0, msk, 64); m1 += __shfl_xor(m1, msk, 64);
            m2 += __shfl_xor(m2, msk, 64); m3 += __shfl_xor(m3, msk, 64);
        }
        if (k == c4) { keep.x = m0; keep.y = m1; keep.z = m2; keep.w = m3; }
    }
    ((float4*)out)[(size_t)n * 16 + k] = keep;
}

// ---------------------------------------------------------------------------
// out = relu(bn3(y3) + x_skip)
__global__ __launch_bounds__(256)
void k_final(const float* __restrict__ y3, const float* __restrict__ ss3,
             const float* __restrict__ x, float* __restrict__ out)
{
    int i = blockIdx.x * 256 + threadIdx.x;   // float4 index
    int c4 = i & 15;
    float4 sc = ((const float4*)ss3)[c4];
    float4 sh = ((const float4*)(ss3 + 64))[c4];
    float4 v  = ((const float4*)y3)[i];
    float4 xs = ((const float4*)x)[i];
    float4 o;
    o.x = fmaxf(fmaf(v.x, sc.x, sh.x) + xs.x, 0.f);
    o.y = fmaxf(fmaf(v.y, sc.y, sh.y) + xs.y, 0.f);
    o.z = fmaxf(fmaf(v.z, sc.z, sh.z) + xs.z, 0.f);
    o.w = fmaxf(fmaf(v.w, sc.w, sh.w) + xs.w, 0.f);
    ((float4*)out)[i] = o;
}

// ---------------------------------------------------------------------------
extern "C" void kernel_launch(void* const* d_in, const int* in_sizes, int n_in,
                              void* d_out, int out_size, void* d_ws, size_t ws_size,
                              hipStream_t stream)
{
    const float* x    = (const float*)d_in[0];
    const float* pos  = (const float*)d_in[1];
    const int*   src  = (const int*)d_in[2];           // edge_index row 0
    const float* W_in = (const float*)d_in[3];
    const float* W_out= (const float*)d_in[4];
    const float* pw1  = (const float*)d_in[5];
    const float* pb1  = (const float*)d_in[6];
    const float* pbg  = (const float*)d_in[7];
    const float* pbb  = (const float*)d_in[8];
    const float* pw2  = (const float*)d_in[9];
    const float* pb2  = (const float*)d_in[10];
    const float* a1g  = (const float*)d_in[11];
    const float* a1b  = (const float*)d_in[12];
    const float* aw1  = (const float*)d_in[13];
    const float* ab1  = (const float*)d_in[14];
    const float* a2g  = (const float*)d_in[15];
    const float* a2b  = (const float*)d_in[16];
    const float* aw2  = (const float*)d_in[17];
    const float* ab2  = (const float*)d_in[18];
    const float* linw = (const float*)d_in[19];
    const float* linb = (const float*)d_in[20];
    const float* srcw = (const float*)d_in[21];
    const float* srcb = (const float*)d_in[22];
    const float* dstw = (const float*)d_in[23];
    const float* dstb = (const float*)d_in[24];
    const float* bn1g = (const float*)d_in[25];
    const float* bn1b = (const float*)d_in[26];
    const float* bn2g = (const float*)d_in[27];
    const float* bn2b = (const float*)d_in[28];
    const float* bn3g = (const float*)d_in[29];
    const float* bn3b = (const float*)d_in[30];
    float* outp = (float*)d_out;

    float* ws = (float*)d_ws;
    const size_t NC = (size_t)N_ * C_;
    float* buf_y    = ws;                 // y1, later y3
    float* buf_asrc = ws + NC;            // a_src, later reused as `out` aggregate
    float* buf_adst = ws + 2 * NC;
    float* buf_hw   = ws + 3 * NC;
    float* buf_t1   = ws + 4 * NC;        // [E,8]
    float* pbase    = ws + 4 * NC + (size_t)E_ * 8;
    float* p_bn1  = pbase;                 // 256*128
    float* p_pos  = p_bn1  + 256 * 128;    // 1024*8
    float* p_abn1 = p_pos  + 1024 * 8;     // 1024*128
    float* p_abn2 = p_abn1 + 1024 * 128;   // 1024*16
    float* p_bn2  = p_abn2 + 1024 * 16;    // 256*128
    float* p_bn3  = p_bn2  + 256 * 128;    // 256*128
    float* ssb    = p_bn3  + 256 * 128;
    float* ss_bn1 = ssb;         // [scale 64][shift 64]
    float* ss_pos = ssb + 128;   // [scale 4][shift 4]
    float* ss_a1  = ssb + 136;   // 128
    float* ss_a2  = ssb + 264;   // 16
    float* ss_bn2 = ssb + 280;   // 128
    float* ss_bn3 = ssb + 408;   // 128

    float* buf_out = buf_asrc;   // reuse after a_src consumed

    // 1) y1 = x @ W_in^T
    k_gemm1_v2<<<512, 256, 0, stream>>>(x, W_in, nullptr, nullptr, buf_y);
    // 2-3) bn1 stats
    k_colstats<<<256, 256, 0, stream>>>(buf_y, p_bn1);
    k_reduce_bn<<<1, 1024, 0, stream>>>(p_bn1, 256, 64, 64, 1.f / N_, bn1g, bn1b, ss_bn1);
    // 4) h = relu(bn1(y1)); a_src/a_dst/hW
    k_gemm3_v2<<<512, 256, 0, stream>>>(buf_y, ss_bn1, srcw, srcb, dstw, dstb, linw, linb,
                                        buf_asrc, buf_adst, buf_hw);
    // 5-6) pos-BN stats
    k_pos_stats<<<1024, 256, 0, stream>>>(pos, src, pw1, pb1, p_pos);
    k_reduce_bn<<<1, 1024, 0, stream>>>(p_pos, 1024, 4, 3, 1.f / E_, pbg, pbb, ss_pos);
    // 7-8) attn_bn1 stats (a recomputed on the fly)
    k_abn1_stats<<<1024, 256, 0, stream>>>(pos, src, buf_asrc, buf_adst,
                                           pw1, pb1, ss_pos, pw2, pb2, p_abn1);
    k_reduce_bn<<<1, 1024, 0, stream>>>(p_abn1, 1024, 64, 64, 1.f / E_, a1g, a1b, ss_a1);
    // 9-10) t1 = relu(abn1(a)) @ attn_w1^T + b1 ; abn2 stats
    k_edge_t1<<<1024, 256, 0, stream>>>(pos, src, buf_asrc, buf_adst,
                                        pw1, pb1, ss_pos, pw2, pb2,
                                        ss_a1, aw1, ab1, buf_t1, p_abn2);
    k_reduce_bn<<<1, 1024, 0, stream>>>(p_abn2, 1024, 8, 8, 1.f / E_, a2g, a2b, ss_a2);
    // 11) softmax + weighted aggregate -> out [N,64]
    k_node_aggr<<<E_ / 256, 256, 0, stream>>>(pos, src, buf_t1, ss_a2, aw2, ab2,
                                              buf_hw, ss_pos, pw1, pb1, pw2, pb2, buf_out);
    // 12-13) bn2 stats
    k_colstats<<<256, 256, 0, stream>>>(buf_out, p_bn2);
    k_reduce_bn<<<1, 1024, 0, stream>>>(p_bn2, 256, 64, 64, 1.f / N_, bn2g, bn2b, ss_bn2);
    // 14) y3 = relu(bn2(out)) @ W_out^T
    k_gemm1_v2<<<512, 256, 0, stream>>>(buf_out, W_out, nullptr, ss_bn2, buf_y);
    // 15-16) bn3 stats
    k_colstats<<<256, 256, 0, stream>>>(buf_y, p_bn3);
    k_reduce_bn<<<1, 1024, 0, stream>>>(p_bn3, 256, 64, 64, 1.f / N_, bn3g, bn3b, ss_bn3);
    // 17) out = relu(bn3(y3) + x)
    k_final<<<(N_ * C_ / 4) / 256, 256, 0, stream>>>(buf_y, ss_bn3, x, outp);

    (void)in_sizes; (void)n_in; (void)out_size; (void)ws_size;
}

// Round 5
// 497.315 us; speedup vs baseline: 1.7988x; 1.7988x over previous
//
#include <hip/hip_runtime.h>
#include <cstddef>

constexpr int N_ = 65536;
constexpr int K_ = 16;
constexpr int E_ = N_ * K_;      // 1048576
constexpr int C_ = 64;
#define EPS_ 1e-5f
#define SW 68   // LDS row stride (words): 68%32=4 -> 2-way worst aliasing on compute reads

// ---------------------------------------------------------------------------
// BN stats reducer (R2 fix: parallel, 4x unrolled, LDS tree; ~<5us).
__global__ __launch_bounds__(1024)
void k_reduce_bn(const float* __restrict__ part, int P, int nchp, int nch,
                 float invM, const float* __restrict__ g,
                 const float* __restrict__ b, float* __restrict__ ss)
{
    int t = threadIdx.x;
    int c = t & (nchp - 1);
    int r = t / nchp;
    int R = 1024 / nchp;
    int stride = 2 * nchp;
    float s0 = 0.f, s1 = 0.f, s2 = 0.f, s3 = 0.f;
    float q0 = 0.f, q1 = 0.f, q2 = 0.f, q3 = 0.f;
    int p = r;
    for (; p + 3 * R < P; p += 4 * R) {
        int i0 = p * stride + c;
        int i1 = (p + R) * stride + c;
        int i2 = (p + 2 * R) * stride + c;
        int i3 = (p + 3 * R) * stride + c;
        s0 += part[i0];        s1 += part[i1];
        s2 += part[i2];        s3 += part[i3];
        q0 += part[i0 + nchp]; q1 += part[i1 + nchp];
        q2 += part[i2 + nchp]; q3 += part[i3 + nchp];
    }
    for (; p < P; p += R) {
        s0 += part[p * stride + c];
        q0 += part[p * stride + nchp + c];
    }
    float s = (s0 + s1) + (s2 + s3);
    float q = (q0 + q1) + (q2 + q3);
    __shared__ float reds[1024], redq[1024];
    reds[t] = s; redq[t] = q;
    __syncthreads();
    for (int off = 512; off >= nchp; off >>= 1) {
        if (t < off) { reds[t] += reds[t + off]; redq[t] += redq[t + off]; }
        __syncthreads();
    }
    if (t < nch) {
        float mean = reds[t] * invM;
        float var  = fmaxf(redq[t] * invM - mean * mean, 0.f);
        float sc = g[t] * rsqrtf(var + EPS_);
        ss[t] = sc;
        ss[nchp + t] = b[t] - mean * sc;
    }
}

// ---------------------------------------------------------------------------
// Column stats over [65536 x 64] row-major buffer. Grid 256 blocks x 256 thr.
__global__ __launch_bounds__(256)
void k_colstats(const float* __restrict__ buf, float* __restrict__ part)
{
    int t = threadIdx.x, c = t & 63, rg = t >> 6;
    float s = 0.f, q = 0.f;
    int base = blockIdx.x * 256 + rg * 64;
    for (int i = 0; i < 64; ++i) {
        float v = buf[(size_t)(base + i) * 64 + c];
        s += v; q = fmaf(v, v, q);
    }
    __shared__ float red[2][256];
    red[0][t] = s; red[1][t] = q;
    __syncthreads();
    if (t < 64) {
        float S = red[0][t] + red[0][t + 64] + red[0][t + 128] + red[0][t + 192];
        float Q = red[1][t] + red[1][t + 64] + red[1][t + 128] + red[1][t + 192];
        part[blockIdx.x * 128 + t]      = S;
        part[blockIdx.x * 128 + 64 + t] = Q;
    }
}

// ---------------------------------------------------------------------------
// R4 post-mortem: wave-uniform scalar-W GEMM was latency-bound (VALUBusy 16%,
// 366us vs 10us VALU floor) once write-amp was fixed — s_load W chains at L2
// latency, 2 waves/SIMD. R5: canonical LDS-tiled GEMM. 64-row tile, X and W
// staged in LDS (stride 68), thread = 4 rows x 4 cols register tile, b128 LDS
// reads (2-way/broadcast = conflict-free), epilogue transposes acc through the
// dead W buffer for coalesced global stores. 1024 blocks = 4 blocks/CU.

__device__ __forceinline__ void stage_x(const float* __restrict__ in,
                                        const float* __restrict__ ss,
                                        float* __restrict__ Xs, int row0, int t)
{
#pragma unroll
    for (int it = 0; it < 4; ++it) {
        int m = t + 256 * it;            // 0..1023 = 64 rows x 16 f4
        int r = m >> 4, j = m & 15;
        float4 v = ((const float4*)in)[(size_t)(row0 + r) * 16 + j];
        if (ss) {
            float4 sc = ((const float4*)ss)[j];
            float4 sh = ((const float4*)(ss + 64))[j];
            v.x = fmaxf(fmaf(v.x, sc.x, sh.x), 0.f);
            v.y = fmaxf(fmaf(v.y, sc.y, sh.y), 0.f);
            v.z = fmaxf(fmaf(v.z, sc.z, sh.z), 0.f);
            v.w = fmaxf(fmaf(v.w, sc.w, sh.w), 0.f);
        }
        *(float4*)&Xs[r * SW + 4 * j] = v;
    }
}

__device__ __forceinline__ void stage_w(const float* __restrict__ W,
                                        float* __restrict__ Ws, int t)
{
#pragma unroll
    for (int it = 0; it < 4; ++it) {
        int m = t + 256 * it;
        int r = m >> 4, j = m & 15;
        *(float4*)&Ws[r * SW + 4 * j] = ((const float4*)W)[m];
    }
}

// acc[r][c] over rows tx+16r, cols ty+16c (tx=t&15, ty=t>>4).
__device__ __forceinline__ void compute_tile(const float* __restrict__ Xs,
                                             const float* __restrict__ Ws,
                                             int tx, int ty, float acc[4][4])
{
#pragma unroll
    for (int r = 0; r < 4; ++r)
#pragma unroll
        for (int c = 0; c < 4; ++c) acc[r][c] = 0.f;
    for (int kc = 0; kc < 16; ++kc) {
        float4 xf[4], wf[4];
#pragma unroll
        for (int r = 0; r < 4; ++r)
            xf[r] = *(const float4*)&Xs[(tx + 16 * r) * SW + 4 * kc];
#pragma unroll
        for (int c = 0; c < 4; ++c)
            wf[c] = *(const float4*)&Ws[(ty + 16 * c) * SW + 4 * kc];
#pragma unroll
        for (int r = 0; r < 4; ++r)
#pragma unroll
            for (int c = 0; c < 4; ++c) {
                acc[r][c] = fmaf(xf[r].x, wf[c].x, acc[r][c]);
                acc[r][c] = fmaf(xf[r].y, wf[c].y, acc[r][c]);
                acc[r][c] = fmaf(xf[r].z, wf[c].z, acc[r][c]);
                acc[r][c] = fmaf(xf[r].w, wf[c].w, acc[r][c]);
            }
    }
}

// Transpose acc tile through LDS buffer (buf = dead Ws) and store coalesced.
__device__ __forceinline__ void write_tile(float* __restrict__ buf, int tx, int ty,
                                           const float acc[4][4],
                                           const float* __restrict__ bias,
                                           float* __restrict__ out, int row0, int t)
{
    __syncthreads();    // all compute reads of buf done
#pragma unroll
    for (int r = 0; r < 4; ++r)
#pragma unroll
        for (int c = 0; c < 4; ++c)
            buf[(tx + 16 * r) * SW + ty + 16 * c] = acc[r][c];
    __syncthreads();
#pragma unroll
    for (int it = 0; it < 4; ++it) {
        int m = t + 256 * it;
        int r = m >> 4, j = m & 15;
        float4 v = *(const float4*)&buf[r * SW + 4 * j];
        if (bias) {
            float4 bv = ((const float4*)bias)[j];
            v.x += bv.x; v.y += bv.y; v.z += bv.z; v.w += bv.w;
        }
        ((float4*)out)[(size_t)(row0 + r) * 16 + j] = v;
    }
    __syncthreads();    // buf free for next stage
}

// y = (optional relu(bn(in))) @ W^T (+bias). 1024 blocks x 256 thr.
__global__ __launch_bounds__(256)
void k_gemm_tile(const float* __restrict__ in, const float* __restrict__ W,
                 const float* __restrict__ bias, const float* __restrict__ ss,
                 float* __restrict__ out)
{
    __shared__ float Xs[64 * SW];
    __shared__ float Ws[64 * SW];
    int t = threadIdx.x, tx = t & 15, ty = t >> 4;
    int row0 = blockIdx.x * 64;
    stage_x(in, ss, Xs, row0, t);
    stage_w(W, Ws, t);
    __syncthreads();
    float acc[4][4];
    compute_tile(Xs, Ws, tx, ty, acc);
    write_tile(Ws, tx, ty, acc, bias, out, row0, t);
}

// h = relu(bn1(y)); oa = h@Wa^T+ba; ob = h@Wb^T+bb; oc = h@Wc^T+bc
__global__ __launch_bounds__(256)
void k_gemm3_tile(const float* __restrict__ y, const float* __restrict__ ss,
                  const float* __restrict__ Wa, const float* __restrict__ ba,
                  const float* __restrict__ Wb, const float* __restrict__ bb,
                  const float* __restrict__ Wc, const float* __restrict__ bc,
                  float* __restrict__ oa, float* __restrict__ ob, float* __restrict__ oc)
{
    __shared__ float Xs[64 * SW];
    __shared__ float Ws[64 * SW];
    int t = threadIdx.x, tx = t & 15, ty = t >> 4;
    int row0 = blockIdx.x * 64;
    stage_x(y, ss, Xs, row0, t);
    stage_w(Wa, Ws, t);
    __syncthreads();
    float acc[4][4];
    compute_tile(Xs, Ws, tx, ty, acc);
    write_tile(Ws, tx, ty, acc, ba, oa, row0, t);
    stage_w(Wb, Ws, t);
    __syncthreads();
    compute_tile(Xs, Ws, tx, ty, acc);
    write_tile(Ws, tx, ty, acc, bb, ob, row0, t);
    stage_w(Wc, Ws, t);
    __syncthreads();
    compute_tile(Xs, Ws, tx, ty, acc);
    write_tile(Ws, tx, ty, acc, bc, oc, row0, t);
}

// ---------------------------------------------------------------------------
// d-vector (pos_nn hidden after BN+ReLU) for one edge. All weights uniform.
__device__ __forceinline__ void compute_d(const float* __restrict__ pos, int si, int di,
                                          const float* __restrict__ pw1,
                                          const float* __restrict__ pb1,
                                          const float* __restrict__ sspos,
                                          float& d0, float& d1, float& d2)
{
    float rx = pos[3 * si + 0] - pos[3 * di + 0];
    float ry = pos[3 * si + 1] - pos[3 * di + 1];
    float rz = pos[3 * si + 2] - pos[3 * di + 2];
    float u0 = fmaf(rx, pw1[0], fmaf(ry, pw1[1], fmaf(rz, pw1[2], pb1[0])));
    float u1 = fmaf(rx, pw1[3], fmaf(ry, pw1[4], fmaf(rz, pw1[5], pb1[1])));
    float u2 = fmaf(rx, pw1[6], fmaf(ry, pw1[7], fmaf(rz, pw1[8], pb1[2])));
    d0 = fmaxf(fmaf(u0, sspos[0], sspos[4]), 0.f);
    d1 = fmaxf(fmaf(u1, sspos[1], sspos[5]), 0.f);
    d2 = fmaxf(fmaf(u2, sspos[2], sspos[6]), 0.f);
}

// ---------------------------------------------------------------------------
// Stats of u = rel @ pos_w1^T + pos_b1 over E edges (3 channels, pad 4).
__global__ __launch_bounds__(256)
void k_pos_stats(const float* __restrict__ pos, const int* __restrict__ src,
                 const float* __restrict__ pw1, const float* __restrict__ pb1,
                 float* __restrict__ part)
{
    float s0 = 0, s1 = 0, s2 = 0, q0 = 0, q1 = 0, q2 = 0;
    int tid = blockIdx.x * 256 + threadIdx.x;
    for (int e = tid; e < E_; e += 1024 * 256) {
        int si = src[e], di = e >> 4;
        float rx = pos[3 * si + 0] - pos[3 * di + 0];
        float ry = pos[3 * si + 1] - pos[3 * di + 1];
        float rz = pos[3 * si + 2] - pos[3 * di + 2];
        float u0 = fmaf(rx, pw1[0], fmaf(ry, pw1[1], fmaf(rz, pw1[2], pb1[0])));
        float u1 = fmaf(rx, pw1[3], fmaf(ry, pw1[4], fmaf(rz, pw1[5], pb1[1])));
        float u2 = fmaf(rx, pw1[6], fmaf(ry, pw1[7], fmaf(rz, pw1[8], pb1[2])));
        s0 += u0; q0 = fmaf(u0, u0, q0);
        s1 += u1; q1 = fmaf(u1, u1, q1);
        s2 += u2; q2 = fmaf(u2, u2, q2);
    }
#pragma unroll
    for (int m = 1; m < 64; m <<= 1) {
        s0 += __shfl_xor(s0, m, 64); s1 += __shfl_xor(s1, m, 64); s2 += __shfl_xor(s2, m, 64);
        q0 += __shfl_xor(q0, m, 64); q1 += __shfl_xor(q1, m, 64); q2 += __shfl_xor(q2, m, 64);
    }
    __shared__ float red[4][8];
    int wv = threadIdx.x >> 6, ln = threadIdx.x & 63;
    if (ln == 0) {
        red[wv][0] = s0; red[wv][1] = s1; red[wv][2] = s2; red[wv][3] = 0.f;
        red[wv][4] = q0; red[wv][5] = q1; red[wv][6] = q2; red[wv][7] = 0.f;
    }
    __syncthreads();
    if (threadIdx.x < 8)
        part[blockIdx.x * 8 + threadIdx.x] =
            red[0][threadIdx.x] + red[1][threadIdx.x] + red[2][threadIdx.x] + red[3][threadIdx.x];
}

// ---------------------------------------------------------------------------
// Stats of a = a_src[src] - a_dst[dst] + delta over E edges (64 channels).
__global__ __launch_bounds__(256)
void k_abn1_stats(const float* __restrict__ pos, const int* __restrict__ src,
                  const float* __restrict__ asrc, const float* __restrict__ adst,
                  const float* __restrict__ pw1, const float* __restrict__ pb1,
                  const float* __restrict__ sspos, const float* __restrict__ pw2,
                  const float* __restrict__ pb2, float* __restrict__ part)
{
    float sacc[64], qacc[64];
#pragma unroll
    for (int i = 0; i < 64; ++i) { sacc[i] = 0.f; qacc[i] = 0.f; }
    int tid = blockIdx.x * 256 + threadIdx.x;
    for (int e = tid; e < E_; e += 1024 * 256) {
        int si = src[e], di = e >> 4;
        float d0, d1, d2;
        compute_d(pos, si, di, pw1, pb1, sspos, d0, d1, d2);
        const float4* ar = (const float4*)(asrc + (size_t)si * 64);
        const float4* dr = (const float4*)(adst + (size_t)di * 64);
#pragma unroll
        for (int c4 = 0; c4 < 16; ++c4) {
            float4 av = ar[c4], dv = dr[c4];
            int c = 4 * c4;
#define PROCA(comp, cc) { \
            float del = fmaf(d0, pw2[3*(cc)+0], fmaf(d1, pw2[3*(cc)+1], fmaf(d2, pw2[3*(cc)+2], pb2[(cc)]))); \
            float a = av.comp - dv.comp + del; \
            sacc[(cc)] += a; qacc[(cc)] = fmaf(a, a, qacc[(cc)]); }
            PROCA(x, c + 0) PROCA(y, c + 1) PROCA(z, c + 2) PROCA(w, c + 3)
#undef PROCA
        }
    }
#pragma unroll
    for (int c = 0; c < 64; ++c) {
        float s = sacc[c], q = qacc[c];
#pragma unroll
        for (int m = 1; m < 64; m <<= 1) { s += __shfl_xor(s, m, 64); q += __shfl_xor(q, m, 64); }
        sacc[c] = s; qacc[c] = q;
    }
    __shared__ float red[4][128];
    int wv = threadIdx.x >> 6, ln = threadIdx.x & 63;
    if (ln == 0) {
#pragma unroll
        for (int c = 0; c < 64; ++c) { red[wv][c] = sacc[c]; red[wv][64 + c] = qacc[c]; }
    }
    __syncthreads();
    if (threadIdx.x < 128)
        part[blockIdx.x * 128 + threadIdx.x] =
            red[0][threadIdx.x] + red[1][threadIdx.x] + red[2][threadIdx.x] + red[3][threadIdx.x];
}

// ---------------------------------------------------------------------------
// t1 = relu(abn1(a)) @ attn_w1^T + attn_b1  [E,8]; also abn2 stats (8 ch).
__global__ __launch_bounds__(256)
void k_edge_t1(const float* __restrict__ pos, const int* __restrict__ src,
               const float* __restrict__ asrc, const float* __restrict__ adst,
               const float* __restrict__ pw1, const float* __restrict__ pb1,
               const float* __restrict__ sspos, const float* __restrict__ pw2,
               const float* __restrict__ pb2, const float* __restrict__ ssa1,
               const float* __restrict__ aw1, const float* __restrict__ ab1,
               float* __restrict__ t1, float* __restrict__ part)
{
    float ssum[8], sq[8];
#pragma unroll
    for (int j = 0; j < 8; ++j) { ssum[j] = 0.f; sq[j] = 0.f; }
    int tid = blockIdx.x * 256 + threadIdx.x;
    for (int e = tid; e < E_; e += 1024 * 256) {
        int si = src[e], di = e >> 4;
        float d0, d1, d2;
        compute_d(pos, si, di, pw1, pb1, sspos, d0, d1, d2);
        const float4* ar = (const float4*)(asrc + (size_t)si * 64);
        const float4* dr = (const float4*)(adst + (size_t)di * 64);
        float tp[8];
#pragma unroll
        for (int j = 0; j < 8; ++j) tp[j] = ab1[j];
#pragma unroll
        for (int c4 = 0; c4 < 16; ++c4) {
            float4 av = ar[c4], dv = dr[c4];
            int c = 4 * c4;
#define PROCB(comp, cc) { \
            float del = fmaf(d0, pw2[3*(cc)+0], fmaf(d1, pw2[3*(cc)+1], fmaf(d2, pw2[3*(cc)+2], pb2[(cc)]))); \
            float a = av.comp - dv.comp + del; \
            float an = fmaxf(fmaf(a, ssa1[(cc)], ssa1[64 + (cc)]), 0.f); \
            _Pragma("unroll") \
            for (int j = 0; j < 8; ++j) tp[j] = fmaf(an, aw1[j * 64 + (cc)], tp[j]); }
            PROCB(x, c + 0) PROCB(y, c + 1) PROCB(z, c + 2) PROCB(w, c + 3)
#undef PROCB
        }
        float4 o0 = {tp[0], tp[1], tp[2], tp[3]};
        float4 o1 = {tp[4], tp[5], tp[6], tp[7]};
        float4* t4 = (float4*)(t1 + (size_t)e * 8);
        t4[0] = o0; t4[1] = o1;
#pragma unroll
        for (int j = 0; j < 8; ++j) { ssum[j] += tp[j]; sq[j] = fmaf(tp[j], tp[j], sq[j]); }
    }
#pragma unroll
    for (int j = 0; j < 8; ++j) {
        float s = ssum[j], q = sq[j];
#pragma unroll
        for (int m = 1; m < 64; m <<= 1) { s += __shfl_xor(s, m, 64); q += __shfl_xor(q, m, 64); }
        ssum[j] = s; sq[j] = q;
    }
    __shared__ float red[4][16];
    int wv = threadIdx.x >> 6, ln = threadIdx.x & 63;
    if (ln == 0) {
#pragma unroll
        for (int j = 0; j < 8; ++j) { red[wv][j] = ssum[j]; red[wv][8 + j] = sq[j]; }
    }
    __syncthreads();
    if (threadIdx.x < 16)
        part[blockIdx.x * 16 + threadIdx.x] =
            red[0][threadIdx.x] + red[1][threadIdx.x] + red[2][threadIdx.x] + red[3][threadIdx.x];
}

// ---------------------------------------------------------------------------
// Final edge pass: softmax over each node's 16 contiguous edges + aggregate.
__global__ __launch_bounds__(256)
void k_node_aggr(const float* __restrict__ pos, const int* __restrict__ src,
                 const float* __restrict__ t1, const float* __restrict__ ssa2,
                 const float* __restrict__ aw2, const float* __restrict__ ab2,
                 const float* __restrict__ hw, const float* __restrict__ sspos,
                 const float* __restrict__ pw1, const float* __restrict__ pb1,
                 const float* __restrict__ pw2, const float* __restrict__ pb2,
                 float* __restrict__ out)
{
    int t = threadIdx.x;
    int e = blockIdx.x * 256 + t;
    int n = e >> 4;
    int k = t & 15;
    const float4* t4 = (const float4*)(t1 + (size_t)e * 8);
    float4 ta = t4[0], tb = t4[1];
    float tv[8] = {ta.x, ta.y, ta.z, ta.w, tb.x, tb.y, tb.z, tb.w};
    float tn[8];
#pragma unroll
    for (int j = 0; j < 8; ++j) tn[j] = fmaxf(fmaf(tv[j], ssa2[j], ssa2[8 + j]), 0.f);
    float al[8];
#pragma unroll
    for (int j = 0; j < 8; ++j) {
        float acc = ab2[j];
#pragma unroll
        for (int i = 0; i < 8; ++i) acc = fmaf(tn[i], aw2[j * 8 + i], acc);
        float m = acc;
#pragma unroll
        for (int msk = 1; msk < 16; msk <<= 1) m = fmaxf(m, __shfl_xor(m, msk, 64));
        float ex = __expf(acc - m);
        float sm = ex;
#pragma unroll
        for (int msk = 1; msk < 16; msk <<= 1) sm += __shfl_xor(sm, msk, 64);
        al[j] = ex / sm;
    }
    int si = src[e];
    float d0, d1, d2;
    compute_d(pos, si, n, pw1, pb1, sspos, d0, d1, d2);
    const float4* hr = (const float4*)(hw + (size_t)si * 64);
    float4 keep = {0.f, 0.f, 0.f, 0.f};
#pragma unroll
    for (int c4 = 0; c4 < 16; ++c4) {
        float4 hv = hr[c4];
        int c = 4 * c4;
        float m0 = (hv.x + fmaf(d0, pw2[3*c+0], fmaf(d1, pw2[3*c+1],  fmaf(d2, pw2[3*c+2],  pb2[c+0])))) * al[(c+0)&7];
        float m1 = (hv.y + fmaf(d0, pw2[3*c+3], fmaf(d1, pw2[3*c+4],  fmaf(d2, pw2[3*c+5],  pb2[c+1])))) * al[(c+1)&7];
        float m2 = (hv.z + fmaf(d0, pw2[3*c+6], fmaf(d1, pw2[3*c+7],  fmaf(d2, pw2[3*c+8],  pb2[c+2])))) * al[(c+2)&7];
        float m3 = (hv.w + fmaf(d0, pw2[3*c+9], fmaf(d1, pw2[3*c+10], fmaf(d2, pw2[3*c+11], pb2[c+3])))) * al[(c+3)&7];
#pragma unroll
        for (int msk = 1; msk < 16; msk <<= 1) {
            m0 += __shfl_xor(m0, msk, 64); m1 += __shfl_xor(m1, msk, 64);
            m2 += __shfl_xor(m2, msk, 64); m3 += __shfl_xor(m3, msk, 64);
        }
        if (k == c4) { keep.x = m0; keep.y = m1; keep.z = m2; keep.w = m3; }
    }
    ((float4*)out)[(size_t)n * 16 + k] = keep;
}

// ---------------------------------------------------------------------------
// out = relu(bn3(y3) + x_skip)
__global__ __launch_bounds__(256)
void k_final(const float* __restrict__ y3, const float* __restrict__ ss3,
             const float* __restrict__ x, float* __restrict__ out)
{
    int i = blockIdx.x * 256 + threadIdx.x;   // float4 index
    int c4 = i & 15;
    float4 sc = ((const float4*)ss3)[c4];
    float4 sh = ((const float4*)(ss3 + 64))[c4];
    float4 v  = ((const float4*)y3)[i];
    float4 xs = ((const float4*)x)[i];
    float4 o;
    o.x = fmaxf(fmaf(v.x, sc.x, sh.x) + xs.x, 0.f);
    o.y = fmaxf(fmaf(v.y, sc.y, sh.y) + xs.y, 0.f);
    o.z = fmaxf(fmaf(v.z, sc.z, sh.z) + xs.z, 0.f);
    o.w = fmaxf(fmaf(v.w, sc.w, sh.w) + xs.w, 0.f);
    ((float4*)out)[i] = o;
}

// ---------------------------------------------------------------------------
extern "C" void kernel_launch(void* const* d_in, const int* in_sizes, int n_in,
                              void* d_out, int out_size, void* d_ws, size_t ws_size,
                              hipStream_t stream)
{
    const float* x    = (const float*)d_in[0];
    const float* pos  = (const float*)d_in[1];
    const int*   src  = (const int*)d_in[2];           // edge_index row 0
    const float* W_in = (const float*)d_in[3];
    const float* W_out= (const float*)d_in[4];
    const float* pw1  = (const float*)d_in[5];
    const float* pb1  = (const float*)d_in[6];
    const float* pbg  = (const float*)d_in[7];
    const float* pbb  = (const float*)d_in[8];
    const float* pw2  = (const float*)d_in[9];
    const float* pb2  = (const float*)d_in[10];
    const float* a1g  = (const float*)d_in[11];
    const float* a1b  = (const float*)d_in[12];
    const float* aw1  = (const float*)d_in[13];
    const float* ab1  = (const float*)d_in[14];
    const float* a2g  = (const float*)d_in[15];
    const float* a2b  = (const float*)d_in[16];
    const float* aw2  = (const float*)d_in[17];
    const float* ab2  = (const float*)d_in[18];
    const float* linw = (const float*)d_in[19];
    const float* linb = (const float*)d_in[20];
    const float* srcw = (const float*)d_in[21];
    const float* srcb = (const float*)d_in[22];
    const float* dstw = (const float*)d_in[23];
    const float* dstb = (const float*)d_in[24];
    const float* bn1g = (const float*)d_in[25];
    const float* bn1b = (const float*)d_in[26];
    const float* bn2g = (const float*)d_in[27];
    const float* bn2b = (const float*)d_in[28];
    const float* bn3g = (const float*)d_in[29];
    const float* bn3b = (const float*)d_in[30];
    float* outp = (float*)d_out;

    float* ws = (float*)d_ws;
    const size_t NC = (size_t)N_ * C_;
    float* buf_y    = ws;                 // y1, later y3
    float* buf_asrc = ws + NC;            // a_src, later reused as `out` aggregate
    float* buf_adst = ws + 2 * NC;
    float* buf_hw   = ws + 3 * NC;
    float* buf_t1   = ws + 4 * NC;        // [E,8]
    float* pbase    = ws + 4 * NC + (size_t)E_ * 8;
    float* p_bn1  = pbase;                 // 256*128
    float* p_pos  = p_bn1  + 256 * 128;    // 1024*8
    float* p_abn1 = p_pos  + 1024 * 8;     // 1024*128
    float* p_abn2 = p_abn1 + 1024 * 128;   // 1024*16
    float* p_bn2  = p_abn2 + 1024 * 16;    // 256*128
    float* p_bn3  = p_bn2  + 256 * 128;    // 256*128
    float* ssb    = p_bn3  + 256 * 128;
    float* ss_bn1 = ssb;         // [scale 64][shift 64]
    float* ss_pos = ssb + 128;   // [scale 4][shift 4]
    float* ss_a1  = ssb + 136;   // 128
    float* ss_a2  = ssb + 264;   // 16
    float* ss_bn2 = ssb + 280;   // 128
    float* ss_bn3 = ssb + 408;   // 128

    float* buf_out = buf_asrc;   // reuse after a_src consumed

    // 1) y1 = x @ W_in^T
    k_gemm_tile<<<1024, 256, 0, stream>>>(x, W_in, nullptr, nullptr, buf_y);
    // 2-3) bn1 stats
    k_colstats<<<256, 256, 0, stream>>>(buf_y, p_bn1);
    k_reduce_bn<<<1, 1024, 0, stream>>>(p_bn1, 256, 64, 64, 1.f / N_, bn1g, bn1b, ss_bn1);
    // 4) h = relu(bn1(y1)); a_src/a_dst/hW
    k_gemm3_tile<<<1024, 256, 0, stream>>>(buf_y, ss_bn1, srcw, srcb, dstw, dstb, linw, linb,
                                           buf_asrc, buf_adst, buf_hw);
    // 5-6) pos-BN stats
    k_pos_stats<<<1024, 256, 0, stream>>>(pos, src, pw1, pb1, p_pos);
    k_reduce_bn<<<1, 1024, 0, stream>>>(p_pos, 1024, 4, 3, 1.f / E_, pbg, pbb, ss_pos);
    // 7-8) attn_bn1 stats (a recomputed on the fly)
    k_abn1_stats<<<1024, 256, 0, stream>>>(pos, src, buf_asrc, buf_adst,
                                           pw1, pb1, ss_pos, pw2, pb2, p_abn1);
    k_reduce_bn<<<1, 1024, 0, stream>>>(p_abn1, 1024, 64, 64, 1.f / E_, a1g, a1b, ss_a1);
    // 9-10) t1 = relu(abn1(a)) @ attn_w1^T + b1 ; abn2 stats
    k_edge_t1<<<1024, 256, 0, stream>>>(pos, src, buf_asrc, buf_adst,
                                        pw1, pb1, ss_pos, pw2, pb2,
                                        ss_a1, aw1, ab1, buf_t1, p_abn2);
    k_reduce_bn<<<1, 1024, 0, stream>>>(p_abn2, 1024, 8, 8, 1.f / E_, a2g, a2b, ss_a2);
    // 11) softmax + weighted aggregate -> out [N,64]
    k_node_aggr<<<E_ / 256, 256, 0, stream>>>(pos, src, buf_t1, ss_a2, aw2, ab2,
                                              buf_hw, ss_pos, pw1, pb1, pw2, pb2, buf_out);
    // 12-13) bn2 stats
    k_colstats<<<256, 256, 0, stream>>>(buf_out, p_bn2);
    k_reduce_bn<<<1, 1024, 0, stream>>>(p_bn2, 256, 64, 64, 1.f / N_, bn2g, bn2b, ss_bn2);
    // 14) y3 = relu(bn2(out)) @ W_out^T
    k_gemm_tile<<<1024, 256, 0, stream>>>(buf_out, W_out, nullptr, ss_bn2, buf_y);
    // 15-16) bn3 stats
    k_colstats<<<256, 256, 0, stream>>>(buf_y, p_bn3);
    k_reduce_bn<<<1, 1024, 0, stream>>>(p_bn3, 256, 64, 64, 1.f / N_, bn3g, bn3b, ss_bn3);
    // 17) out = relu(bn3(y3) + x)
    k_final<<<(N_ * C_ / 4) / 256, 256, 0, stream>>>(buf_y, ss_bn3, x, outp);

    (void)in_sizes; (void)n_in; (void)out_size; (void)ws_size;
}

// Round 6
// 435.896 us; speedup vs baseline: 2.0523x; 1.1409x over previous
//
#include <hip/hip_runtime.h>
#include <cstddef>

constexpr int N_ = 65536;
constexpr int K_ = 16;
constexpr int E_ = N_ * K_;      // 1048576
constexpr int C_ = 64;
#define EPS_ 1e-5f
#define SW 68   // LDS row stride (words) for GEMM tiles

// ---------------------------------------------------------------------------
// BN stats reducer (R2 fix: parallel, 4x unrolled, LDS tree; ~<5us).
__global__ __launch_bounds__(1024)
void k_reduce_bn(const float* __restrict__ part, int P, int nchp, int nch,
                 float invM, const float* __restrict__ g,
                 const float* __restrict__ b, float* __restrict__ ss)
{
    int t = threadIdx.x;
    int c = t & (nchp - 1);
    int r = t / nchp;
    int R = 1024 / nchp;
    int stride = 2 * nchp;
    float s0 = 0.f, s1 = 0.f, s2 = 0.f, s3 = 0.f;
    float q0 = 0.f, q1 = 0.f, q2 = 0.f, q3 = 0.f;
    int p = r;
    for (; p + 3 * R < P; p += 4 * R) {
        int i0 = p * stride + c;
        int i1 = (p + R) * stride + c;
        int i2 = (p + 2 * R) * stride + c;
        int i3 = (p + 3 * R) * stride + c;
        s0 += part[i0];        s1 += part[i1];
        s2 += part[i2];        s3 += part[i3];
        q0 += part[i0 + nchp]; q1 += part[i1 + nchp];
        q2 += part[i2 + nchp]; q3 += part[i3 + nchp];
    }
    for (; p < P; p += R) {
        s0 += part[p * stride + c];
        q0 += part[p * stride + nchp + c];
    }
    float s = (s0 + s1) + (s2 + s3);
    float q = (q0 + q1) + (q2 + q3);
    __shared__ float reds[1024], redq[1024];
    reds[t] = s; redq[t] = q;
    __syncthreads();
    for (int off = 512; off >= nchp; off >>= 1) {
        if (t < off) { reds[t] += reds[t + off]; redq[t] += redq[t + off]; }
        __syncthreads();
    }
    if (t < nch) {
        float mean = reds[t] * invM;
        float var  = fmaxf(redq[t] * invM - mean * mean, 0.f);
        float sc = g[t] * rsqrtf(var + EPS_);
        ss[t] = sc;
        ss[nchp + t] = b[t] - mean * sc;
    }
}

// ---------------------------------------------------------------------------
// Column stats over [65536 x 64] row-major buffer. Grid 256 blocks x 256 thr.
__global__ __launch_bounds__(256)
void k_colstats(const float* __restrict__ buf, float* __restrict__ part)
{
    int t = threadIdx.x, c = t & 63, rg = t >> 6;
    float s = 0.f, q = 0.f;
    int base = blockIdx.x * 256 + rg * 64;
    for (int i = 0; i < 64; ++i) {
        float v = buf[(size_t)(base + i) * 64 + c];
        s += v; q = fmaf(v, v, q);
    }
    __shared__ float red[2][256];
    red[0][t] = s; red[1][t] = q;
    __syncthreads();
    if (t < 64) {
        float S = red[0][t] + red[0][t + 64] + red[0][t + 128] + red[0][t + 192];
        float Q = red[1][t] + red[1][t + 64] + red[1][t + 128] + red[1][t + 192];
        part[blockIdx.x * 128 + t]      = S;
        part[blockIdx.x * 128 + 64 + t] = Q;
    }
}

// ---------------------------------------------------------------------------
// R5 GEMM structure (LDS-tiled, coalesced) — kept from R5.
__device__ __forceinline__ void stage_x(const float* __restrict__ in,
                                        const float* __restrict__ ss,
                                        float* __restrict__ Xs, int row0, int t)
{
#pragma unroll
    for (int it = 0; it < 4; ++it) {
        int m = t + 256 * it;
        int r = m >> 4, j = m & 15;
        float4 v = ((const float4*)in)[(size_t)(row0 + r) * 16 + j];
        if (ss) {
            float4 sc = ((const float4*)ss)[j];
            float4 sh = ((const float4*)(ss + 64))[j];
            v.x = fmaxf(fmaf(v.x, sc.x, sh.x), 0.f);
            v.y = fmaxf(fmaf(v.y, sc.y, sh.y), 0.f);
            v.z = fmaxf(fmaf(v.z, sc.z, sh.z), 0.f);
            v.w = fmaxf(fmaf(v.w, sc.w, sh.w), 0.f);
        }
        *(float4*)&Xs[r * SW + 4 * j] = v;
    }
}

__device__ __forceinline__ void stage_w(const float* __restrict__ W,
                                        float* __restrict__ Ws, int t)
{
#pragma unroll
    for (int it = 0; it < 4; ++it) {
        int m = t + 256 * it;
        int r = m >> 4, j = m & 15;
        *(float4*)&Ws[r * SW + 4 * j] = ((const float4*)W)[m];
    }
}

__device__ __forceinline__ void compute_tile(const float* __restrict__ Xs,
                                             const float* __restrict__ Ws,
                                             int tx, int ty, float acc[4][4])
{
#pragma unroll
    for (int r = 0; r < 4; ++r)
#pragma unroll
        for (int c = 0; c < 4; ++c) acc[r][c] = 0.f;
    for (int kc = 0; kc < 16; ++kc) {
        float4 xf[4], wf[4];
#pragma unroll
        for (int r = 0; r < 4; ++r)
            xf[r] = *(const float4*)&Xs[(tx + 16 * r) * SW + 4 * kc];
#pragma unroll
        for (int c = 0; c < 4; ++c)
            wf[c] = *(const float4*)&Ws[(ty + 16 * c) * SW + 4 * kc];
#pragma unroll
        for (int r = 0; r < 4; ++r)
#pragma unroll
            for (int c = 0; c < 4; ++c) {
                acc[r][c] = fmaf(xf[r].x, wf[c].x, acc[r][c]);
                acc[r][c] = fmaf(xf[r].y, wf[c].y, acc[r][c]);
                acc[r][c] = fmaf(xf[r].z, wf[c].z, acc[r][c]);
                acc[r][c] = fmaf(xf[r].w, wf[c].w, acc[r][c]);
            }
    }
}

__device__ __forceinline__ void write_tile(float* __restrict__ buf, int tx, int ty,
                                           const float acc[4][4],
                                           const float* __restrict__ bias,
                                           float* __restrict__ out, int row0, int t)
{
    __syncthreads();
#pragma unroll
    for (int r = 0; r < 4; ++r)
#pragma unroll
        for (int c = 0; c < 4; ++c)
            buf[(tx + 16 * r) * SW + ty + 16 * c] = acc[r][c];
    __syncthreads();
#pragma unroll
    for (int it = 0; it < 4; ++it) {
        int m = t + 256 * it;
        int r = m >> 4, j = m & 15;
        float4 v = *(const float4*)&buf[r * SW + 4 * j];
        if (bias) {
            float4 bv = ((const float4*)bias)[j];
            v.x += bv.x; v.y += bv.y; v.z += bv.z; v.w += bv.w;
        }
        ((float4*)out)[(size_t)(row0 + r) * 16 + j] = v;
    }
    __syncthreads();
}

__global__ __launch_bounds__(256)
void k_gemm_tile(const float* __restrict__ in, const float* __restrict__ W,
                 const float* __restrict__ bias, const float* __restrict__ ss,
                 float* __restrict__ out)
{
    __shared__ float Xs[64 * SW];
    __shared__ float Ws[64 * SW];
    int t = threadIdx.x, tx = t & 15, ty = t >> 4;
    int row0 = blockIdx.x * 64;
    stage_x(in, ss, Xs, row0, t);
    stage_w(W, Ws, t);
    __syncthreads();
    float acc[4][4];
    compute_tile(Xs, Ws, tx, ty, acc);
    write_tile(Ws, tx, ty, acc, bias, out, row0, t);
}

__global__ __launch_bounds__(256)
void k_gemm3_tile(const float* __restrict__ y, const float* __restrict__ ss,
                  const float* __restrict__ Wa, const float* __restrict__ ba,
                  const float* __restrict__ Wb, const float* __restrict__ bb,
                  const float* __restrict__ Wc, const float* __restrict__ bc,
                  float* __restrict__ oa, float* __restrict__ ob, float* __restrict__ oc)
{
    __shared__ float Xs[64 * SW];
    __shared__ float Ws[64 * SW];
    int t = threadIdx.x, tx = t & 15, ty = t >> 4;
    int row0 = blockIdx.x * 64;
    stage_x(y, ss, Xs, row0, t);
    stage_w(Wa, Ws, t);
    __syncthreads();
    float acc[4][4];
    compute_tile(Xs, Ws, tx, ty, acc);
    write_tile(Ws, tx, ty, acc, ba, oa, row0, t);
    stage_w(Wb, Ws, t);
    __syncthreads();
    compute_tile(Xs, Ws, tx, ty, acc);
    write_tile(Ws, tx, ty, acc, bb, ob, row0, t);
    stage_w(Wc, Ws, t);
    __syncthreads();
    compute_tile(Xs, Ws, tx, ty, acc);
    write_tile(Ws, tx, ty, acc, bc, oc, row0, t);
}

// ---------------------------------------------------------------------------
// d-vector (pos_nn hidden after BN+ReLU) for one edge. All weights uniform.
__device__ __forceinline__ void compute_d(const float* __restrict__ pos, int si, int di,
                                          const float* __restrict__ pw1,
                                          const float* __restrict__ pb1,
                                          const float* __restrict__ sspos,
                                          float& d0, float& d1, float& d2)
{
    float rx = pos[3 * si + 0] - pos[3 * di + 0];
    float ry = pos[3 * si + 1] - pos[3 * di + 1];
    float rz = pos[3 * si + 2] - pos[3 * di + 2];
    float u0 = fmaf(rx, pw1[0], fmaf(ry, pw1[1], fmaf(rz, pw1[2], pb1[0])));
    float u1 = fmaf(rx, pw1[3], fmaf(ry, pw1[4], fmaf(rz, pw1[5], pb1[1])));
    float u2 = fmaf(rx, pw1[6], fmaf(ry, pw1[7], fmaf(rz, pw1[8], pb1[2])));
    d0 = fmaxf(fmaf(u0, sspos[0], sspos[4]), 0.f);
    d1 = fmaxf(fmaf(u1, sspos[1], sspos[5]), 0.f);
    d2 = fmaxf(fmaf(u2, sspos[2], sspos[6]), 0.f);
}

// ---------------------------------------------------------------------------
// Stats of u = rel @ pos_w1^T + pos_b1 over E edges (3 channels, pad 4).
__global__ __launch_bounds__(256)
void k_pos_stats(const float* __restrict__ pos, const int* __restrict__ src,
                 const float* __restrict__ pw1, const float* __restrict__ pb1,
                 float* __restrict__ part)
{
    float s0 = 0, s1 = 0, s2 = 0, q0 = 0, q1 = 0, q2 = 0;
    int tid = blockIdx.x * 256 + threadIdx.x;
    for (int e = tid; e < E_; e += 1024 * 256) {
        int si = src[e], di = e >> 4;
        float rx = pos[3 * si + 0] - pos[3 * di + 0];
        float ry = pos[3 * si + 1] - pos[3 * di + 1];
        float rz = pos[3 * si + 2] - pos[3 * di + 2];
        float u0 = fmaf(rx, pw1[0], fmaf(ry, pw1[1], fmaf(rz, pw1[2], pb1[0])));
        float u1 = fmaf(rx, pw1[3], fmaf(ry, pw1[4], fmaf(rz, pw1[5], pb1[1])));
        float u2 = fmaf(rx, pw1[6], fmaf(ry, pw1[7], fmaf(rz, pw1[8], pb1[2])));
        s0 += u0; q0 = fmaf(u0, u0, q0);
        s1 += u1; q1 = fmaf(u1, u1, q1);
        s2 += u2; q2 = fmaf(u2, u2, q2);
    }
#pragma unroll
    for (int m = 1; m < 64; m <<= 1) {
        s0 += __shfl_xor(s0, m, 64); s1 += __shfl_xor(s1, m, 64); s2 += __shfl_xor(s2, m, 64);
        q0 += __shfl_xor(q0, m, 64); q1 += __shfl_xor(q1, m, 64); q2 += __shfl_xor(q2, m, 64);
    }
    __shared__ float red[4][8];
    int wv = threadIdx.x >> 6, ln = threadIdx.x & 63;
    if (ln == 0) {
        red[wv][0] = s0; red[wv][1] = s1; red[wv][2] = s2; red[wv][3] = 0.f;
        red[wv][4] = q0; red[wv][5] = q1; red[wv][6] = q2; red[wv][7] = 0.f;
    }
    __syncthreads();
    if (threadIdx.x < 8)
        part[blockIdx.x * 8 + threadIdx.x] =
            red[0][threadIdx.x] + red[1][threadIdx.x] + red[2][threadIdx.x] + red[3][threadIdx.x];
}

// ---------------------------------------------------------------------------
// R6: coalesced-gather edge kernels. 16 lanes/row: lane l owns channels
// 4l..4l+3, one float4 per row gather (256 B contiguous per group). Wave = 4
// groups processing 4 consecutive edges. Per-lane loop-invariant weight regs.

// Stats of a = a_src[src] - a_dst[dst] + delta over E edges (64 channels).
// Grid 1024 x 256: block covers 1024 contiguous edges; wave covers 256.
__global__ __launch_bounds__(256)
void k_abn1_stats(const float* __restrict__ pos, const int* __restrict__ src,
                  const float* __restrict__ asrc, const float* __restrict__ adst,
                  const float* __restrict__ pw1, const float* __restrict__ pb1,
                  const float* __restrict__ sspos, const float* __restrict__ pw2,
                  const float* __restrict__ pb2, float* __restrict__ part)
{
    int t = threadIdx.x;
    int l = t & 15, sub = (t >> 4) & 3, wv = t >> 6;
    int c0 = 4 * l;
    float4 p0 = *(const float4*)(pw2 + 12 * l);
    float4 p1 = *(const float4*)(pw2 + 12 * l + 4);
    float4 p2 = *(const float4*)(pw2 + 12 * l + 8);
    float4 pb = *(const float4*)(pb2 + c0);
    float sa0 = 0, sa1 = 0, sa2 = 0, sa3 = 0;
    float qa0 = 0, qa1 = 0, qa2 = 0, qa3 = 0;
    int base = blockIdx.x * 1024 + wv * 256 + sub;
    for (int i = 0; i < 64; ++i) {
        int e = base + 4 * i;
        int si = src[e], di = e >> 4;
        float d0, d1, d2;
        compute_d(pos, si, di, pw1, pb1, sspos, d0, d1, d2);
        float4 av = *(const float4*)(asrc + (size_t)si * 64 + c0);
        float4 dv = *(const float4*)(adst + (size_t)di * 64 + c0);
        float del0 = fmaf(d0, p0.x, fmaf(d1, p0.y, fmaf(d2, p0.z, pb.x)));
        float del1 = fmaf(d0, p0.w, fmaf(d1, p1.x, fmaf(d2, p1.y, pb.y)));
        float del2 = fmaf(d0, p1.z, fmaf(d1, p1.w, fmaf(d2, p2.x, pb.z)));
        float del3 = fmaf(d0, p2.y, fmaf(d1, p2.z, fmaf(d2, p2.w, pb.w)));
        float a0 = av.x - dv.x + del0;
        float a1 = av.y - dv.y + del1;
        float a2 = av.z - dv.z + del2;
        float a3 = av.w - dv.w + del3;
        sa0 += a0; qa0 = fmaf(a0, a0, qa0);
        sa1 += a1; qa1 = fmaf(a1, a1, qa1);
        sa2 += a2; qa2 = fmaf(a2, a2, qa2);
        sa3 += a3; qa3 = fmaf(a3, a3, qa3);
    }
    // reduce across the 4 groups of the wave
#pragma unroll
    for (int m = 16; m <= 32; m <<= 1) {
        sa0 += __shfl_xor(sa0, m, 64); sa1 += __shfl_xor(sa1, m, 64);
        sa2 += __shfl_xor(sa2, m, 64); sa3 += __shfl_xor(sa3, m, 64);
        qa0 += __shfl_xor(qa0, m, 64); qa1 += __shfl_xor(qa1, m, 64);
        qa2 += __shfl_xor(qa2, m, 64); qa3 += __shfl_xor(qa3, m, 64);
    }
    __shared__ float red[4][128];
    if ((t & 63) < 16) {
        red[wv][c0 + 0] = sa0; red[wv][c0 + 1] = sa1;
        red[wv][c0 + 2] = sa2; red[wv][c0 + 3] = sa3;
        red[wv][64 + c0 + 0] = qa0; red[wv][64 + c0 + 1] = qa1;
        red[wv][64 + c0 + 2] = qa2; red[wv][64 + c0 + 3] = qa3;
    }
    __syncthreads();
    if (t < 128)
        part[blockIdx.x * 128 + t] = red[0][t] + red[1][t] + red[2][t] + red[3][t];
}

// ---------------------------------------------------------------------------
// t1 = relu(abn1(a)) @ attn_w1^T + attn_b1  [E,8]; also abn2 stats (8 ch).
__global__ __launch_bounds__(256)
void k_edge_t1(const float* __restrict__ pos, const int* __restrict__ src,
               const float* __restrict__ asrc, const float* __restrict__ adst,
               const float* __restrict__ pw1, const float* __restrict__ pb1,
               const float* __restrict__ sspos, const float* __restrict__ pw2,
               const float* __restrict__ pb2, const float* __restrict__ ssa1,
               const float* __restrict__ aw1, const float* __restrict__ ab1,
               float* __restrict__ t1, float* __restrict__ part)
{
    int t = threadIdx.x;
    int l = t & 15, sub = (t >> 4) & 3, wv = t >> 6;
    int c0 = 4 * l;
    float4 p0 = *(const float4*)(pw2 + 12 * l);
    float4 p1 = *(const float4*)(pw2 + 12 * l + 4);
    float4 p2 = *(const float4*)(pw2 + 12 * l + 8);
    float4 pb = *(const float4*)(pb2 + c0);
    float4 sc = *(const float4*)(ssa1 + c0);
    float4 sh = *(const float4*)(ssa1 + 64 + c0);
    float4 w1[8];
#pragma unroll
    for (int jj = 0; jj < 8; ++jj) w1[jj] = *(const float4*)(aw1 + jj * 64 + c0);
    float sse0 = 0, sse1 = 0, sse2 = 0, sse3 = 0;
    float ssq0 = 0, ssq1 = 0, ssq2 = 0, ssq3 = 0;
    int base = blockIdx.x * 1024 + wv * 256 + sub;
    for (int i = 0; i < 64; ++i) {
        int e = base + 4 * i;
        int si = src[e], di = e >> 4;
        float d0, d1, d2;
        compute_d(pos, si, di, pw1, pb1, sspos, d0, d1, d2);
        float4 av = *(const float4*)(asrc + (size_t)si * 64 + c0);
        float4 dv = *(const float4*)(adst + (size_t)di * 64 + c0);
        float del0 = fmaf(d0, p0.x, fmaf(d1, p0.y, fmaf(d2, p0.z, pb.x)));
        float del1 = fmaf(d0, p0.w, fmaf(d1, p1.x, fmaf(d2, p1.y, pb.y)));
        float del2 = fmaf(d0, p1.z, fmaf(d1, p1.w, fmaf(d2, p2.x, pb.z)));
        float del3 = fmaf(d0, p2.y, fmaf(d1, p2.z, fmaf(d2, p2.w, pb.w)));
        float an0 = fmaxf(fmaf(av.x - dv.x + del0, sc.x, sh.x), 0.f);
        float an1 = fmaxf(fmaf(av.y - dv.y + del1, sc.y, sh.y), 0.f);
        float an2 = fmaxf(fmaf(av.z - dv.z + del2, sc.z, sh.z), 0.f);
        float an3 = fmaxf(fmaf(av.w - dv.w + del3, sc.w, sh.w), 0.f);
        float tp[8];
#pragma unroll
        for (int jj = 0; jj < 8; ++jj)
            tp[jj] = fmaf(an0, w1[jj].x, fmaf(an1, w1[jj].y,
                     fmaf(an2, w1[jj].z, an3 * w1[jj].w)));
        // butterfly over the 16 lanes of the group
#pragma unroll
        for (int m = 1; m < 16; m <<= 1)
#pragma unroll
            for (int jj = 0; jj < 8; ++jj) tp[jj] += __shfl_xor(tp[jj], m, 64);
        float o0 = (l == 0) ? tp[0] : tp[4];
        float o1 = (l == 0) ? tp[1] : tp[5];
        float o2 = (l == 0) ? tp[2] : tp[6];
        float o3 = (l == 0) ? tp[3] : tp[7];
        if (l < 2) {
            float bias0 = ab1[4 * l + 0], bias1 = ab1[4 * l + 1];
            float bias2 = ab1[4 * l + 2], bias3 = ab1[4 * l + 3];
            o0 += bias0; o1 += bias1; o2 += bias2; o3 += bias3;
            *(float4*)(t1 + (size_t)e * 8 + 4 * l) = make_float4(o0, o1, o2, o3);
            sse0 += o0; ssq0 = fmaf(o0, o0, ssq0);
            sse1 += o1; ssq1 = fmaf(o1, o1, ssq1);
            sse2 += o2; ssq2 = fmaf(o2, o2, ssq2);
            sse3 += o3; ssq3 = fmaf(o3, o3, ssq3);
        }
    }
#pragma unroll
    for (int m = 16; m <= 32; m <<= 1) {
        sse0 += __shfl_xor(sse0, m, 64); sse1 += __shfl_xor(sse1, m, 64);
        sse2 += __shfl_xor(sse2, m, 64); sse3 += __shfl_xor(sse3, m, 64);
        ssq0 += __shfl_xor(ssq0, m, 64); ssq1 += __shfl_xor(ssq1, m, 64);
        ssq2 += __shfl_xor(ssq2, m, 64); ssq3 += __shfl_xor(ssq3, m, 64);
    }
    __shared__ float red[4][16];
    if ((t & 63) < 2) {
        red[wv][4 * l + 0] = sse0; red[wv][4 * l + 1] = sse1;
        red[wv][4 * l + 2] = sse2; red[wv][4 * l + 3] = sse3;
        red[wv][8 + 4 * l + 0] = ssq0; red[wv][8 + 4 * l + 1] = ssq1;
        red[wv][8 + 4 * l + 2] = ssq2; red[wv][8 + 4 * l + 3] = ssq3;
    }
    __syncthreads();
    if (t < 16)
        part[blockIdx.x * 16 + t] = red[0][t] + red[1][t] + red[2][t] + red[3][t];
}

// ---------------------------------------------------------------------------
// Softmax + weighted aggregate, group-per-node. Grid 1024 x 256 (64 nodes/blk).
__global__ __launch_bounds__(256)
void k_node_aggr(const float* __restrict__ pos, const int* __restrict__ src,
                 const float* __restrict__ t1, const float* __restrict__ ssa2,
                 const float* __restrict__ aw2, const float* __restrict__ ab2,
                 const float* __restrict__ hw, const float* __restrict__ sspos,
                 const float* __restrict__ pw1, const float* __restrict__ pb1,
                 const float* __restrict__ pw2, const float* __restrict__ pb2,
                 float* __restrict__ out)
{
    __shared__ float alds[16][196];   // [group][k*12 + ch8], padded strides
    int t = threadIdx.x, l = t & 15, g = t >> 4;
    int c0 = 4 * l;
    float4 p0 = *(const float4*)(pw2 + 12 * l);
    float4 p1 = *(const float4*)(pw2 + 12 * l + 4);
    float4 p2 = *(const float4*)(pw2 + 12 * l + 8);
    float4 pb = *(const float4*)(pb2 + c0);
    int alof = (l & 1) * 4;
    for (int round = 0; round < 4; ++round) {
        int n = blockIdx.x * 64 + round * 16 + g;
        int e = n * 16 + l;
        // ---- phase A: per-edge attention logits + softmax over the group
        const float4* t4 = (const float4*)(t1 + (size_t)e * 8);
        float4 ta = t4[0], tb = t4[1];
        float tv[8] = {ta.x, ta.y, ta.z, ta.w, tb.x, tb.y, tb.z, tb.w};
        float tn[8];
#pragma unroll
        for (int j = 0; j < 8; ++j)
            tn[j] = fmaxf(fmaf(tv[j], ssa2[j], ssa2[8 + j]), 0.f);
        float al[8];
#pragma unroll
        for (int j = 0; j < 8; ++j) {
            float acc = ab2[j];
#pragma unroll
            for (int i = 0; i < 8; ++i) acc = fmaf(tn[i], aw2[j * 8 + i], acc);
            float m = acc;
#pragma unroll
            for (int msk = 1; msk < 16; msk <<= 1) m = fmaxf(m, __shfl_xor(m, msk, 64));
            float ex = __expf(acc - m);
            float sm = ex;
#pragma unroll
            for (int msk = 1; msk < 16; msk <<= 1) sm += __shfl_xor(sm, msk, 64);
            al[j] = ex / sm;
        }
        *(float4*)&alds[g][l * 12]     = make_float4(al[0], al[1], al[2], al[3]);
        *(float4*)&alds[g][l * 12 + 4] = make_float4(al[4], al[5], al[6], al[7]);
        int silane = src[e];
        float pnx = pos[3 * n + 0], pny = pos[3 * n + 1], pnz = pos[3 * n + 2];
        // ---- phase B: accumulate own 4 channels over the node's 16 edges
        float a0 = 0.f, a1 = 0.f, a2 = 0.f, a3 = 0.f;
#pragma unroll 4
        for (int k = 0; k < 16; ++k) {
            int sk = __shfl(silane, k, 16);
            float rx = pos[3 * sk + 0] - pnx;
            float ry = pos[3 * sk + 1] - pny;
            float rz = pos[3 * sk + 2] - pnz;
            float u0 = fmaf(rx, pw1[0], fmaf(ry, pw1[1], fmaf(rz, pw1[2], pb1[0])));
            float u1 = fmaf(rx, pw1[3], fmaf(ry, pw1[4], fmaf(rz, pw1[5], pb1[1])));
            float u2 = fmaf(rx, pw1[6], fmaf(ry, pw1[7], fmaf(rz, pw1[8], pb1[2])));
            float d0 = fmaxf(fmaf(u0, sspos[0], sspos[4]), 0.f);
            float d1 = fmaxf(fmaf(u1, sspos[1], sspos[5]), 0.f);
            float d2 = fmaxf(fmaf(u2, sspos[2], sspos[6]), 0.f);
            float4 hv = *(const float4*)(hw + (size_t)sk * 64 + c0);
            float4 alv = *(const float4*)&alds[g][k * 12 + alof];
            float del0 = fmaf(d0, p0.x, fmaf(d1, p0.y, fmaf(d2, p0.z, pb.x)));
            float del1 = fmaf(d0, p0.w, fmaf(d1, p1.x, fmaf(d2, p1.y, pb.y)));
            float del2 = fmaf(d0, p1.z, fmaf(d1, p1.w, fmaf(d2, p2.x, pb.z)));
            float del3 = fmaf(d0, p2.y, fmaf(d1, p2.z, fmaf(d2, p2.w, pb.w)));
            a0 = fmaf(alv.x, hv.x + del0, a0);
            a1 = fmaf(alv.y, hv.y + del1, a1);
            a2 = fmaf(alv.z, hv.z + del2, a2);
            a3 = fmaf(alv.w, hv.w + del3, a3);
        }
        *(float4*)(out + (size_t)n * 64 + c0) = make_float4(a0, a1, a2, a3);
    }
}

// ---------------------------------------------------------------------------
// out = relu(bn3(y3) + x_skip)
__global__ __launch_bounds__(256)
void k_final(const float* __restrict__ y3, const float* __restrict__ ss3,
             const float* __restrict__ x, float* __restrict__ out)
{
    int i = blockIdx.x * 256 + threadIdx.x;   // float4 index
    int c4 = i & 15;
    float4 sc = ((const float4*)ss3)[c4];
    float4 sh = ((const float4*)(ss3 + 64))[c4];
    float4 v  = ((const float4*)y3)[i];
    float4 xs = ((const float4*)x)[i];
    float4 o;
    o.x = fmaxf(fmaf(v.x, sc.x, sh.x) + xs.x, 0.f);
    o.y = fmaxf(fmaf(v.y, sc.y, sh.y) + xs.y, 0.f);
    o.z = fmaxf(fmaf(v.z, sc.z, sh.z) + xs.z, 0.f);
    o.w = fmaxf(fmaf(v.w, sc.w, sh.w) + xs.w, 0.f);
    ((float4*)out)[i] = o;
}

// ---------------------------------------------------------------------------
extern "C" void kernel_launch(void* const* d_in, const int* in_sizes, int n_in,
                              void* d_out, int out_size, void* d_ws, size_t ws_size,
                              hipStream_t stream)
{
    const float* x    = (const float*)d_in[0];
    const float* pos  = (const float*)d_in[1];
    const int*   src  = (const int*)d_in[2];           // edge_index row 0
    const float* W_in = (const float*)d_in[3];
    const float* W_out= (const float*)d_in[4];
    const float* pw1  = (const float*)d_in[5];
    const float* pb1  = (const float*)d_in[6];
    const float* pbg  = (const float*)d_in[7];
    const float* pbb  = (const float*)d_in[8];
    const float* pw2  = (const float*)d_in[9];
    const float* pb2  = (const float*)d_in[10];
    const float* a1g  = (const float*)d_in[11];
    const float* a1b  = (const float*)d_in[12];
    const float* aw1  = (const float*)d_in[13];
    const float* ab1  = (const float*)d_in[14];
    const float* a2g  = (const float*)d_in[15];
    const float* a2b  = (const float*)d_in[16];
    const float* aw2  = (const float*)d_in[17];
    const float* ab2  = (const float*)d_in[18];
    const float* linw = (const float*)d_in[19];
    const float* linb = (const float*)d_in[20];
    const float* srcw = (const float*)d_in[21];
    const float* srcb = (const float*)d_in[22];
    const float* dstw = (const float*)d_in[23];
    const float* dstb = (const float*)d_in[24];
    const float* bn1g = (const float*)d_in[25];
    const float* bn1b = (const float*)d_in[26];
    const float* bn2g = (const float*)d_in[27];
    const float* bn2b = (const float*)d_in[28];
    const float* bn3g = (const float*)d_in[29];
    const float* bn3b = (const float*)d_in[30];
    float* outp = (float*)d_out;

    float* ws = (float*)d_ws;
    const size_t NC = (size_t)N_ * C_;
    float* buf_y    = ws;                 // y1, later y3
    float* buf_asrc = ws + NC;            // a_src, later reused as `out` aggregate
    float* buf_adst = ws + 2 * NC;
    float* buf_hw   = ws + 3 * NC;
    float* buf_t1   = ws + 4 * NC;        // [E,8]
    float* pbase    = ws + 4 * NC + (size_t)E_ * 8;
    float* p_bn1  = pbase;                 // 256*128
    float* p_pos  = p_bn1  + 256 * 128;    // 1024*8
    float* p_abn1 = p_pos  + 1024 * 8;     // 1024*128
    float* p_abn2 = p_abn1 + 1024 * 128;   // 1024*16
    float* p_bn2  = p_abn2 + 1024 * 16;    // 256*128
    float* p_bn3  = p_bn2  + 256 * 128;    // 256*128
    float* ssb    = p_bn3  + 256 * 128;
    float* ss_bn1 = ssb;         // [scale 64][shift 64]
    float* ss_pos = ssb + 128;   // [scale 4][shift 4]
    float* ss_a1  = ssb + 136;   // 128
    float* ss_a2  = ssb + 264;   // 16
    float* ss_bn2 = ssb + 280;   // 128
    float* ss_bn3 = ssb + 408;   // 128

    float* buf_out = buf_asrc;   // reuse after a_src consumed

    // 1) y1 = x @ W_in^T
    k_gemm_tile<<<1024, 256, 0, stream>>>(x, W_in, nullptr, nullptr, buf_y);
    // 2-3) bn1 stats
    k_colstats<<<256, 256, 0, stream>>>(buf_y, p_bn1);
    k_reduce_bn<<<1, 1024, 0, stream>>>(p_bn1, 256, 64, 64, 1.f / N_, bn1g, bn1b, ss_bn1);
    // 4) h = relu(bn1(y1)); a_src/a_dst/hW
    k_gemm3_tile<<<1024, 256, 0, stream>>>(buf_y, ss_bn1, srcw, srcb, dstw, dstb, linw, linb,
                                           buf_asrc, buf_adst, buf_hw);
    // 5-6) pos-BN stats
    k_pos_stats<<<1024, 256, 0, stream>>>(pos, src, pw1, pb1, p_pos);
    k_reduce_bn<<<1, 1024, 0, stream>>>(p_pos, 1024, 4, 3, 1.f / E_, pbg, pbb, ss_pos);
    // 7-8) attn_bn1 stats (a recomputed on the fly, coalesced gathers)
    k_abn1_stats<<<1024, 256, 0, stream>>>(pos, src, buf_asrc, buf_adst,
                                           pw1, pb1, ss_pos, pw2, pb2, p_abn1);
    k_reduce_bn<<<1, 1024, 0, stream>>>(p_abn1, 1024, 64, 64, 1.f / E_, a1g, a1b, ss_a1);
    // 9-10) t1 = relu(abn1(a)) @ attn_w1^T + b1 ; abn2 stats
    k_edge_t1<<<1024, 256, 0, stream>>>(pos, src, buf_asrc, buf_adst,
                                        pw1, pb1, ss_pos, pw2, pb2,
                                        ss_a1, aw1, ab1, buf_t1, p_abn2);
    k_reduce_bn<<<1, 1024, 0, stream>>>(p_abn2, 1024, 8, 8, 1.f / E_, a2g, a2b, ss_a2);
    // 11) softmax + weighted aggregate -> out [N,64]
    k_node_aggr<<<1024, 256, 0, stream>>>(pos, src, buf_t1, ss_a2, aw2, ab2,
                                          buf_hw, ss_pos, pw1, pb1, pw2, pb2, buf_out);
    // 12-13) bn2 stats
    k_colstats<<<256, 256, 0, stream>>>(buf_out, p_bn2);
    k_reduce_bn<<<1, 1024, 0, stream>>>(p_bn2, 256, 64, 64, 1.f / N_, bn2g, bn2b, ss_bn2);
    // 14) y3 = relu(bn2(out)) @ W_out^T
    k_gemm_tile<<<1024, 256, 0, stream>>>(buf_out, W_out, nullptr, ss_bn2, buf_y);
    // 15-16) bn3 stats
    k_colstats<<<256, 256, 0, stream>>>(buf_y, p_bn3);
    k_reduce_bn<<<1, 1024, 0, stream>>>(p_bn3, 256, 64, 64, 1.f / N_, bn3g, bn3b, ss_bn3);
    // 17) out = relu(bn3(y3) + x)
    k_final<<<(N_ * C_ / 4) / 256, 256, 0, stream>>>(buf_y, ss_bn3, x, outp);

    (void)in_sizes; (void)n_in; (void)out_size; (void)ws_size;
}

// Round 7
// 391.335 us; speedup vs baseline: 2.2859x; 1.1139x over previous
//
#include <hip/hip_runtime.h>
#include <cstddef>

constexpr int N_ = 65536;
constexpr int K_ = 16;
constexpr int E_ = N_ * K_;      // 1048576
constexpr int C_ = 64;
#define EPS_ 1e-5f
#define SW 68   // LDS row stride (words) for GEMM tiles

// ---------------------------------------------------------------------------
// BN stats reducer (R2 fix: parallel, 4x unrolled, LDS tree).
__global__ __launch_bounds__(1024)
void k_reduce_bn(const float* __restrict__ part, int P, int nchp, int nch,
                 float invM, const float* __restrict__ g,
                 const float* __restrict__ b, float* __restrict__ ss)
{
    int t = threadIdx.x;
    int c = t & (nchp - 1);
    int r = t / nchp;
    int R = 1024 / nchp;
    int stride = 2 * nchp;
    float s0 = 0.f, s1 = 0.f, s2 = 0.f, s3 = 0.f;
    float q0 = 0.f, q1 = 0.f, q2 = 0.f, q3 = 0.f;
    int p = r;
    for (; p + 3 * R < P; p += 4 * R) {
        int i0 = p * stride + c;
        int i1 = (p + R) * stride + c;
        int i2 = (p + 2 * R) * stride + c;
        int i3 = (p + 3 * R) * stride + c;
        s0 += part[i0];        s1 += part[i1];
        s2 += part[i2];        s3 += part[i3];
        q0 += part[i0 + nchp]; q1 += part[i1 + nchp];
        q2 += part[i2 + nchp]; q3 += part[i3 + nchp];
    }
    for (; p < P; p += R) {
        s0 += part[p * stride + c];
        q0 += part[p * stride + nchp + c];
    }
    float s = (s0 + s1) + (s2 + s3);
    float q = (q0 + q1) + (q2 + q3);
    __shared__ float reds[1024], redq[1024];
    reds[t] = s; redq[t] = q;
    __syncthreads();
    for (int off = 512; off >= nchp; off >>= 1) {
        if (t < off) { reds[t] += reds[t + off]; redq[t] += redq[t + off]; }
        __syncthreads();
    }
    if (t < nch) {
        float mean = reds[t] * invM;
        float var  = fmaxf(redq[t] * invM - mean * mean, 0.f);
        float sc = g[t] * rsqrtf(var + EPS_);
        ss[t] = sc;
        ss[nchp + t] = b[t] - mean * sc;
    }
}

// ---------------------------------------------------------------------------
// Column stats over [65536 x 64] row-major buffer. Grid 256 blocks x 256 thr.
__global__ __launch_bounds__(256)
void k_colstats(const float* __restrict__ buf, float* __restrict__ part)
{
    int t = threadIdx.x, c = t & 63, rg = t >> 6;
    float s = 0.f, q = 0.f;
    int base = blockIdx.x * 256 + rg * 64;
    for (int i = 0; i < 64; ++i) {
        float v = buf[(size_t)(base + i) * 64 + c];
        s += v; q = fmaf(v, v, q);
    }
    __shared__ float red[2][256];
    red[0][t] = s; red[1][t] = q;
    __syncthreads();
    if (t < 64) {
        float S = red[0][t] + red[0][t + 64] + red[0][t + 128] + red[0][t + 192];
        float Q = red[1][t] + red[1][t + 64] + red[1][t + 128] + red[1][t + 192];
        part[blockIdx.x * 128 + t]      = S;
        part[blockIdx.x * 128 + 64 + t] = Q;
    }
}

// ---------------------------------------------------------------------------
// R5 GEMM structure (LDS-tiled, coalesced) — kept.
__device__ __forceinline__ void stage_x(const float* __restrict__ in,
                                        const float* __restrict__ ss,
                                        float* __restrict__ Xs, int row0, int t)
{
#pragma unroll
    for (int it = 0; it < 4; ++it) {
        int m = t + 256 * it;
        int r = m >> 4, j = m & 15;
        float4 v = ((const float4*)in)[(size_t)(row0 + r) * 16 + j];
        if (ss) {
            float4 sc = ((const float4*)ss)[j];
            float4 sh = ((const float4*)(ss + 64))[j];
            v.x = fmaxf(fmaf(v.x, sc.x, sh.x), 0.f);
            v.y = fmaxf(fmaf(v.y, sc.y, sh.y), 0.f);
            v.z = fmaxf(fmaf(v.z, sc.z, sh.z), 0.f);
            v.w = fmaxf(fmaf(v.w, sc.w, sh.w), 0.f);
        }
        *(float4*)&Xs[r * SW + 4 * j] = v;
    }
}

__device__ __forceinline__ void stage_w(const float* __restrict__ W,
                                        float* __restrict__ Ws, int t)
{
#pragma unroll
    for (int it = 0; it < 4; ++it) {
        int m = t + 256 * it;
        int r = m >> 4, j = m & 15;
        *(float4*)&Ws[r * SW + 4 * j] = ((const float4*)W)[m];
    }
}

__device__ __forceinline__ void compute_tile(const float* __restrict__ Xs,
                                             const float* __restrict__ Ws,
                                             int tx, int ty, float acc[4][4])
{
#pragma unroll
    for (int r = 0; r < 4; ++r)
#pragma unroll
        for (int c = 0; c < 4; ++c) acc[r][c] = 0.f;
    for (int kc = 0; kc < 16; ++kc) {
        float4 xf[4], wf[4];
#pragma unroll
        for (int r = 0; r < 4; ++r)
            xf[r] = *(const float4*)&Xs[(tx + 16 * r) * SW + 4 * kc];
#pragma unroll
        for (int c = 0; c < 4; ++c)
            wf[c] = *(const float4*)&Ws[(ty + 16 * c) * SW + 4 * kc];
#pragma unroll
        for (int r = 0; r < 4; ++r)
#pragma unroll
            for (int c = 0; c < 4; ++c) {
                acc[r][c] = fmaf(xf[r].x, wf[c].x, acc[r][c]);
                acc[r][c] = fmaf(xf[r].y, wf[c].y, acc[r][c]);
                acc[r][c] = fmaf(xf[r].z, wf[c].z, acc[r][c]);
                acc[r][c] = fmaf(xf[r].w, wf[c].w, acc[r][c]);
            }
    }
}

__device__ __forceinline__ void write_tile(float* __restrict__ buf, int tx, int ty,
                                           const float acc[4][4],
                                           const float* __restrict__ bias,
                                           float* __restrict__ out, int row0, int t)
{
    __syncthreads();
#pragma unroll
    for (int r = 0; r < 4; ++r)
#pragma unroll
        for (int c = 0; c < 4; ++c)
            buf[(tx + 16 * r) * SW + ty + 16 * c] = acc[r][c];
    __syncthreads();
#pragma unroll
    for (int it = 0; it < 4; ++it) {
        int m = t + 256 * it;
        int r = m >> 4, j = m & 15;
        float4 v = *(const float4*)&buf[r * SW + 4 * j];
        if (bias) {
            float4 bv = ((const float4*)bias)[j];
            v.x += bv.x; v.y += bv.y; v.z += bv.z; v.w += bv.w;
        }
        ((float4*)out)[(size_t)(row0 + r) * 16 + j] = v;
    }
    __syncthreads();
}

__global__ __launch_bounds__(256)
void k_gemm_tile(const float* __restrict__ in, const float* __restrict__ W,
                 const float* __restrict__ bias, const float* __restrict__ ss,
                 float* __restrict__ out)
{
    __shared__ float Xs[64 * SW];
    __shared__ float Ws[64 * SW];
    int t = threadIdx.x, tx = t & 15, ty = t >> 4;
    int row0 = blockIdx.x * 64;
    stage_x(in, ss, Xs, row0, t);
    stage_w(W, Ws, t);
    __syncthreads();
    float acc[4][4];
    compute_tile(Xs, Ws, tx, ty, acc);
    write_tile(Ws, tx, ty, acc, bias, out, row0, t);
}

__global__ __launch_bounds__(256)
void k_gemm3_tile(const float* __restrict__ y, const float* __restrict__ ss,
                  const float* __restrict__ Wa, const float* __restrict__ ba,
                  const float* __restrict__ Wb, const float* __restrict__ bb,
                  const float* __restrict__ Wc, const float* __restrict__ bc,
                  float* __restrict__ oa, float* __restrict__ ob, float* __restrict__ oc)
{
    __shared__ float Xs[64 * SW];
    __shared__ float Ws[64 * SW];
    int t = threadIdx.x, tx = t & 15, ty = t >> 4;
    int row0 = blockIdx.x * 64;
    stage_x(y, ss, Xs, row0, t);
    stage_w(Wa, Ws, t);
    __syncthreads();
    float acc[4][4];
    compute_tile(Xs, Ws, tx, ty, acc);
    write_tile(Ws, tx, ty, acc, ba, oa, row0, t);
    stage_w(Wb, Ws, t);
    __syncthreads();
    compute_tile(Xs, Ws, tx, ty, acc);
    write_tile(Ws, tx, ty, acc, bb, ob, row0, t);
    stage_w(Wc, Ws, t);
    __syncthreads();
    compute_tile(Xs, Ws, tx, ty, acc);
    write_tile(Ws, tx, ty, acc, bc, oc, row0, t);
}

// ---------------------------------------------------------------------------
// Stats of u = rel @ pos_w1^T + pos_b1 over E edges (3 channels, pad 4).
__global__ __launch_bounds__(256)
void k_pos_stats(const float* __restrict__ pos, const int* __restrict__ src,
                 const float* __restrict__ pw1, const float* __restrict__ pb1,
                 float* __restrict__ part)
{
    float s0 = 0, s1 = 0, s2 = 0, q0 = 0, q1 = 0, q2 = 0;
    int tid = blockIdx.x * 256 + threadIdx.x;
    for (int e = tid; e < E_; e += 1024 * 256) {
        int si = src[e], di = e >> 4;
        float rx = pos[3 * si + 0] - pos[3 * di + 0];
        float ry = pos[3 * si + 1] - pos[3 * di + 1];
        float rz = pos[3 * si + 2] - pos[3 * di + 2];
        float u0 = fmaf(rx, pw1[0], fmaf(ry, pw1[1], fmaf(rz, pw1[2], pb1[0])));
        float u1 = fmaf(rx, pw1[3], fmaf(ry, pw1[4], fmaf(rz, pw1[5], pb1[1])));
        float u2 = fmaf(rx, pw1[6], fmaf(ry, pw1[7], fmaf(rz, pw1[8], pb1[2])));
        s0 += u0; q0 = fmaf(u0, u0, q0);
        s1 += u1; q1 = fmaf(u1, u1, q1);
        s2 += u2; q2 = fmaf(u2, u2, q2);
    }
#pragma unroll
    for (int m = 1; m < 64; m <<= 1) {
        s0 += __shfl_xor(s0, m, 64); s1 += __shfl_xor(s1, m, 64); s2 += __shfl_xor(s2, m, 64);
        q0 += __shfl_xor(q0, m, 64); q1 += __shfl_xor(q1, m, 64); q2 += __shfl_xor(q2, m, 64);
    }
    __shared__ float red[4][8];
    int wv = threadIdx.x >> 6, ln = threadIdx.x & 63;
    if (ln == 0) {
        red[wv][0] = s0; red[wv][1] = s1; red[wv][2] = s2; red[wv][3] = 0.f;
        red[wv][4] = q0; red[wv][5] = q1; red[wv][6] = q2; red[wv][7] = 0.f;
    }
    __syncthreads();
    if (threadIdx.x < 8)
        part[blockIdx.x * 8 + threadIdx.x] =
            red[0][threadIdx.x] + red[1][threadIdx.x] + red[2][threadIdx.x] + red[3][threadIdx.x];
}

// ---------------------------------------------------------------------------
// R7: group-per-node edge kernels. Group of 16 lanes owns one node's 16
// edges: adst[n], pos[n], src[n*16+l] loaded once; per-edge only the asrc/pos
// gather. Lane l owns channels 4l..4l+3.

// Stats of a = a_src[src]-a_dst[dst]+delta. Grid 2048 x 256 (32 nodes/block).
__global__ __launch_bounds__(256)
void k_abn1_stats(const float* __restrict__ pos, const int* __restrict__ src,
                  const float* __restrict__ asrc, const float* __restrict__ adst,
                  const float* __restrict__ pw1, const float* __restrict__ pb1,
                  const float* __restrict__ sspos, const float* __restrict__ pw2,
                  const float* __restrict__ pb2, float* __restrict__ part)
{
    int t = threadIdx.x;
    int l = t & 15, g = t >> 4, wv = t >> 6;
    int c0 = 4 * l;
    float4 p0 = *(const float4*)(pw2 + 12 * l);
    float4 p1 = *(const float4*)(pw2 + 12 * l + 4);
    float4 p2 = *(const float4*)(pw2 + 12 * l + 8);
    float4 pb = *(const float4*)(pb2 + c0);
    float sa0 = 0, sa1 = 0, sa2 = 0, sa3 = 0;
    float qa0 = 0, qa1 = 0, qa2 = 0, qa3 = 0;
#pragma unroll
    for (int nn = 0; nn < 2; ++nn) {
        int n = blockIdx.x * 32 + nn * 16 + g;
        float4 dv = *(const float4*)(adst + (size_t)n * 64 + c0);
        float pnx = pos[3 * n + 0], pny = pos[3 * n + 1], pnz = pos[3 * n + 2];
        int si_l = src[n * 16 + l];
        for (int k = 0; k < 16; ++k) {
            int si = __shfl(si_l, k, 16);
            float rx = pos[3 * si + 0] - pnx;
            float ry = pos[3 * si + 1] - pny;
            float rz = pos[3 * si + 2] - pnz;
            float u0 = fmaf(rx, pw1[0], fmaf(ry, pw1[1], fmaf(rz, pw1[2], pb1[0])));
            float u1 = fmaf(rx, pw1[3], fmaf(ry, pw1[4], fmaf(rz, pw1[5], pb1[1])));
            float u2 = fmaf(rx, pw1[6], fmaf(ry, pw1[7], fmaf(rz, pw1[8], pb1[2])));
            float d0 = fmaxf(fmaf(u0, sspos[0], sspos[4]), 0.f);
            float d1 = fmaxf(fmaf(u1, sspos[1], sspos[5]), 0.f);
            float d2 = fmaxf(fmaf(u2, sspos[2], sspos[6]), 0.f);
            float4 av = *(const float4*)(asrc + (size_t)si * 64 + c0);
            float del0 = fmaf(d0, p0.x, fmaf(d1, p0.y, fmaf(d2, p0.z, pb.x)));
            float del1 = fmaf(d0, p0.w, fmaf(d1, p1.x, fmaf(d2, p1.y, pb.y)));
            float del2 = fmaf(d0, p1.z, fmaf(d1, p1.w, fmaf(d2, p2.x, pb.z)));
            float del3 = fmaf(d0, p2.y, fmaf(d1, p2.z, fmaf(d2, p2.w, pb.w)));
            float a0 = av.x - dv.x + del0;
            float a1 = av.y - dv.y + del1;
            float a2 = av.z - dv.z + del2;
            float a3 = av.w - dv.w + del3;
            sa0 += a0; qa0 = fmaf(a0, a0, qa0);
            sa1 += a1; qa1 = fmaf(a1, a1, qa1);
            sa2 += a2; qa2 = fmaf(a2, a2, qa2);
            sa3 += a3; qa3 = fmaf(a3, a3, qa3);
        }
    }
#pragma unroll
    for (int m = 16; m <= 32; m <<= 1) {
        sa0 += __shfl_xor(sa0, m, 64); sa1 += __shfl_xor(sa1, m, 64);
        sa2 += __shfl_xor(sa2, m, 64); sa3 += __shfl_xor(sa3, m, 64);
        qa0 += __shfl_xor(qa0, m, 64); qa1 += __shfl_xor(qa1, m, 64);
        qa2 += __shfl_xor(qa2, m, 64); qa3 += __shfl_xor(qa3, m, 64);
    }
    __shared__ float red[4][128];
    if ((t & 63) < 16) {
        red[wv][c0 + 0] = sa0; red[wv][c0 + 1] = sa1;
        red[wv][c0 + 2] = sa2; red[wv][c0 + 3] = sa3;
        red[wv][64 + c0 + 0] = qa0; red[wv][64 + c0 + 1] = qa1;
        red[wv][64 + c0 + 2] = qa2; red[wv][64 + c0 + 3] = qa3;
    }
    __syncthreads();
    if (t < 128)
        part[blockIdx.x * 128 + t] = red[0][t] + red[1][t] + red[2][t] + red[3][t];
}

// ---------------------------------------------------------------------------
// t1 = relu(abn1(a)) @ attn_w1^T + attn_b1  [E,8]; also abn2 stats (8 ch).
// Reduce-scatter butterfly: 8 shuffles/edge; lane l<8 ends with channel
// ch(l) = 4*(l&1) + 2*((l>>1)&1) + ((l>>2)&1). Grid 2048 x 256.
__global__ __launch_bounds__(256)
void k_edge_t1(const float* __restrict__ pos, const int* __restrict__ src,
               const float* __restrict__ asrc, const float* __restrict__ adst,
               const float* __restrict__ pw1, const float* __restrict__ pb1,
               const float* __restrict__ sspos, const float* __restrict__ pw2,
               const float* __restrict__ pb2, const float* __restrict__ ssa1,
               const float* __restrict__ aw1, const float* __restrict__ ab1,
               float* __restrict__ t1, float* __restrict__ part)
{
    int t = threadIdx.x;
    int l = t & 15, g = t >> 4, wv = t >> 6;
    int c0 = 4 * l;
    int ch = 4 * (l & 1) + 2 * ((l >> 1) & 1) + ((l >> 2) & 1);
    float abv = ab1[ch];
    float4 p0 = *(const float4*)(pw2 + 12 * l);
    float4 p1 = *(const float4*)(pw2 + 12 * l + 4);
    float4 p2 = *(const float4*)(pw2 + 12 * l + 8);
    float4 pb = *(const float4*)(pb2 + c0);
    float4 sc = *(const float4*)(ssa1 + c0);
    float4 sh = *(const float4*)(ssa1 + 64 + c0);
    float4 w1[8];
#pragma unroll
    for (int jj = 0; jj < 8; ++jj) w1[jj] = *(const float4*)(aw1 + jj * 64 + c0);
    float sse = 0.f, ssq = 0.f;
#pragma unroll
    for (int nn = 0; nn < 2; ++nn) {
        int n = blockIdx.x * 32 + nn * 16 + g;
        float4 dv = *(const float4*)(adst + (size_t)n * 64 + c0);
        float pnx = pos[3 * n + 0], pny = pos[3 * n + 1], pnz = pos[3 * n + 2];
        int si_l = src[n * 16 + l];
        for (int k = 0; k < 16; ++k) {
            int si = __shfl(si_l, k, 16);
            float rx = pos[3 * si + 0] - pnx;
            float ry = pos[3 * si + 1] - pny;
            float rz = pos[3 * si + 2] - pnz;
            float u0 = fmaf(rx, pw1[0], fmaf(ry, pw1[1], fmaf(rz, pw1[2], pb1[0])));
            float u1 = fmaf(rx, pw1[3], fmaf(ry, pw1[4], fmaf(rz, pw1[5], pb1[1])));
            float u2 = fmaf(rx, pw1[6], fmaf(ry, pw1[7], fmaf(rz, pw1[8], pb1[2])));
            float d0 = fmaxf(fmaf(u0, sspos[0], sspos[4]), 0.f);
            float d1 = fmaxf(fmaf(u1, sspos[1], sspos[5]), 0.f);
            float d2 = fmaxf(fmaf(u2, sspos[2], sspos[6]), 0.f);
            float4 av = *(const float4*)(asrc + (size_t)si * 64 + c0);
            float del0 = fmaf(d0, p0.x, fmaf(d1, p0.y, fmaf(d2, p0.z, pb.x)));
            float del1 = fmaf(d0, p0.w, fmaf(d1, p1.x, fmaf(d2, p1.y, pb.y)));
            float del2 = fmaf(d0, p1.z, fmaf(d1, p1.w, fmaf(d2, p2.x, pb.z)));
            float del3 = fmaf(d0, p2.y, fmaf(d1, p2.z, fmaf(d2, p2.w, pb.w)));
            float an0 = fmaxf(fmaf(av.x - dv.x + del0, sc.x, sh.x), 0.f);
            float an1 = fmaxf(fmaf(av.y - dv.y + del1, sc.y, sh.y), 0.f);
            float an2 = fmaxf(fmaf(av.z - dv.z + del2, sc.z, sh.z), 0.f);
            float an3 = fmaxf(fmaf(av.w - dv.w + del3, sc.w, sh.w), 0.f);
            float tp[8];
#pragma unroll
            for (int jj = 0; jj < 8; ++jj)
                tp[jj] = fmaf(an0, w1[jj].x, fmaf(an1, w1[jj].y,
                         fmaf(an2, w1[jj].z, an3 * w1[jj].w)));
            // reduce-scatter: 8 -> 4 -> 2 -> 1 values, 4+2+1+1 shuffles
            float s4[4];
#pragma unroll
            for (int j = 0; j < 4; ++j) {
                float send = (l & 1) ? tp[j] : tp[j + 4];
                float recv = __shfl_xor(send, 1, 64);
                s4[j] = ((l & 1) ? tp[j + 4] : tp[j]) + recv;
            }
            float s2[2];
#pragma unroll
            for (int j = 0; j < 2; ++j) {
                float send = (l & 2) ? s4[j] : s4[j + 2];
                float recv = __shfl_xor(send, 2, 64);
                s2[j] = ((l & 2) ? s4[j + 2] : s4[j]) + recv;
            }
            float send = (l & 4) ? s2[0] : s2[1];
            float recv = __shfl_xor(send, 4, 64);
            float s1 = ((l & 4) ? s2[1] : s2[0]) + recv;
            s1 += __shfl_xor(s1, 8, 64);
            float o = s1 + abv;
            if (l < 8) t1[(size_t)(n * 16 + k) * 8 + ch] = o;
            sse += o; ssq = fmaf(o, o, ssq);
        }
    }
#pragma unroll
    for (int m = 16; m <= 32; m <<= 1) {
        sse += __shfl_xor(sse, m, 64);
        ssq += __shfl_xor(ssq, m, 64);
    }
    __shared__ float red[4][16];
    if ((t & 63) < 8) { red[wv][ch] = sse; red[wv][8 + ch] = ssq; }
    __syncthreads();
    if (t < 16)
        part[blockIdx.x * 16 + t] = red[0][t] + red[1][t] + red[2][t] + red[3][t];
}

// ---------------------------------------------------------------------------
// Softmax + weighted aggregate, group-per-node. Grid 4096 x 256 (16 nodes/blk).
__global__ __launch_bounds__(256)
void k_node_aggr(const float* __restrict__ pos, const int* __restrict__ src,
                 const float* __restrict__ t1, const float* __restrict__ ssa2,
                 const float* __restrict__ aw2, const float* __restrict__ ab2,
                 const float* __restrict__ hw, const float* __restrict__ sspos,
                 const float* __restrict__ pw1, const float* __restrict__ pb1,
                 const float* __restrict__ pw2, const float* __restrict__ pb2,
                 float* __restrict__ out)
{
    __shared__ float alds[16][196];   // [group][k*12 + ch8]
    int t = threadIdx.x, l = t & 15, g = t >> 4;
    int c0 = 4 * l;
    float4 p0 = *(const float4*)(pw2 + 12 * l);
    float4 p1 = *(const float4*)(pw2 + 12 * l + 4);
    float4 p2 = *(const float4*)(pw2 + 12 * l + 8);
    float4 pb = *(const float4*)(pb2 + c0);
    int alof = (l & 1) * 4;
    int n = blockIdx.x * 16 + g;
    int e = n * 16 + l;
    // ---- phase A: per-edge attention logits + softmax over the group
    const float4* t4 = (const float4*)(t1 + (size_t)e * 8);
    float4 ta = t4[0], tb = t4[1];
    float tv[8] = {ta.x, ta.y, ta.z, ta.w, tb.x, tb.y, tb.z, tb.w};
    float tn[8];
#pragma unroll
    for (int j = 0; j < 8; ++j)
        tn[j] = fmaxf(fmaf(tv[j], ssa2[j], ssa2[8 + j]), 0.f);
    float al[8];
#pragma unroll
    for (int j = 0; j < 8; ++j) {
        float acc = ab2[j];
#pragma unroll
        for (int i = 0; i < 8; ++i) acc = fmaf(tn[i], aw2[j * 8 + i], acc);
        float m = acc;
#pragma unroll
        for (int msk = 1; msk < 16; msk <<= 1) m = fmaxf(m, __shfl_xor(m, msk, 64));
        float ex = __expf(acc - m);
        float sm = ex;
#pragma unroll
        for (int msk = 1; msk < 16; msk <<= 1) sm += __shfl_xor(sm, msk, 64);
        al[j] = ex / sm;
    }
    *(float4*)&alds[g][l * 12]     = make_float4(al[0], al[1], al[2], al[3]);
    *(float4*)&alds[g][l * 12 + 4] = make_float4(al[4], al[5], al[6], al[7]);
    int silane = src[e];
    float pnx = pos[3 * n + 0], pny = pos[3 * n + 1], pnz = pos[3 * n + 2];
    // ---- phase B: accumulate own 4 channels over the node's 16 edges
    float a0 = 0.f, a1 = 0.f, a2 = 0.f, a3 = 0.f;
#pragma unroll 4
    for (int k = 0; k < 16; ++k) {
        int sk = __shfl(silane, k, 16);
        float rx = pos[3 * sk + 0] - pnx;
        float ry = pos[3 * sk + 1] - pny;
        float rz = pos[3 * sk + 2] - pnz;
        float u0 = fmaf(rx, pw1[0], fmaf(ry, pw1[1], fmaf(rz, pw1[2], pb1[0])));
        float u1 = fmaf(rx, pw1[3], fmaf(ry, pw1[4], fmaf(rz, pw1[5], pb1[1])));
        float u2 = fmaf(rx, pw1[6], fmaf(ry, pw1[7], fmaf(rz, pw1[8], pb1[2])));
        float d0 = fmaxf(fmaf(u0, sspos[0], sspos[4]), 0.f);
        float d1 = fmaxf(fmaf(u1, sspos[1], sspos[5]), 0.f);
        float d2 = fmaxf(fmaf(u2, sspos[2], sspos[6]), 0.f);
        float4 hv = *(const float4*)(hw + (size_t)sk * 64 + c0);
        float4 alv = *(const float4*)&alds[g][k * 12 + alof];
        float del0 = fmaf(d0, p0.x, fmaf(d1, p0.y, fmaf(d2, p0.z, pb.x)));
        float del1 = fmaf(d0, p0.w, fmaf(d1, p1.x, fmaf(d2, p1.y, pb.y)));
        float del2 = fmaf(d0, p1.z, fmaf(d1, p1.w, fmaf(d2, p2.x, pb.z)));
        float del3 = fmaf(d0, p2.y, fmaf(d1, p2.z, fmaf(d2, p2.w, pb.w)));
        a0 = fmaf(alv.x, hv.x + del0, a0);
        a1 = fmaf(alv.y, hv.y + del1, a1);
        a2 = fmaf(alv.z, hv.z + del2, a2);
        a3 = fmaf(alv.w, hv.w + del3, a3);
    }
    *(float4*)(out + (size_t)n * 64 + c0) = make_float4(a0, a1, a2, a3);
}

// ---------------------------------------------------------------------------
// out = relu(bn3(y3) + x_skip)
__global__ __launch_bounds__(256)
void k_final(const float* __restrict__ y3, const float* __restrict__ ss3,
             const float* __restrict__ x, float* __restrict__ out)
{
    int i = blockIdx.x * 256 + threadIdx.x;   // float4 index
    int c4 = i & 15;
    float4 sc = ((const float4*)ss3)[c4];
    float4 sh = ((const float4*)(ss3 + 64))[c4];
    float4 v  = ((const float4*)y3)[i];
    float4 xs = ((const float4*)x)[i];
    float4 o;
    o.x = fmaxf(fmaf(v.x, sc.x, sh.x) + xs.x, 0.f);
    o.y = fmaxf(fmaf(v.y, sc.y, sh.y) + xs.y, 0.f);
    o.z = fmaxf(fmaf(v.z, sc.z, sh.z) + xs.z, 0.f);
    o.w = fmaxf(fmaf(v.w, sc.w, sh.w) + xs.w, 0.f);
    ((float4*)out)[i] = o;
}

// ---------------------------------------------------------------------------
extern "C" void kernel_launch(void* const* d_in, const int* in_sizes, int n_in,
                              void* d_out, int out_size, void* d_ws, size_t ws_size,
                              hipStream_t stream)
{
    const float* x    = (const float*)d_in[0];
    const float* pos  = (const float*)d_in[1];
    const int*   src  = (const int*)d_in[2];           // edge_index row 0
    const float* W_in = (const float*)d_in[3];
    const float* W_out= (const float*)d_in[4];
    const float* pw1  = (const float*)d_in[5];
    const float* pb1  = (const float*)d_in[6];
    const float* pbg  = (const float*)d_in[7];
    const float* pbb  = (const float*)d_in[8];
    const float* pw2  = (const float*)d_in[9];
    const float* pb2  = (const float*)d_in[10];
    const float* a1g  = (const float*)d_in[11];
    const float* a1b  = (const float*)d_in[12];
    const float* aw1  = (const float*)d_in[13];
    const float* ab1  = (const float*)d_in[14];
    const float* a2g  = (const float*)d_in[15];
    const float* a2b  = (const float*)d_in[16];
    const float* aw2  = (const float*)d_in[17];
    const float* ab2  = (const float*)d_in[18];
    const float* linw = (const float*)d_in[19];
    const float* linb = (const float*)d_in[20];
    const float* srcw = (const float*)d_in[21];
    const float* srcb = (const float*)d_in[22];
    const float* dstw = (const float*)d_in[23];
    const float* dstb = (const float*)d_in[24];
    const float* bn1g = (const float*)d_in[25];
    const float* bn1b = (const float*)d_in[26];
    const float* bn2g = (const float*)d_in[27];
    const float* bn2b = (const float*)d_in[28];
    const float* bn3g = (const float*)d_in[29];
    const float* bn3b = (const float*)d_in[30];
    float* outp = (float*)d_out;

    float* ws = (float*)d_ws;
    const size_t NC = (size_t)N_ * C_;
    float* buf_y    = ws;                 // y1, later y3
    float* buf_asrc = ws + NC;            // a_src, later reused as `out` aggregate
    float* buf_adst = ws + 2 * NC;
    float* buf_hw   = ws + 3 * NC;
    float* buf_t1   = ws + 4 * NC;        // [E,8]
    float* pbase    = ws + 4 * NC + (size_t)E_ * 8;
    float* p_bn1  = pbase;                 // 256*128
    float* p_pos  = p_bn1  + 256 * 128;    // 1024*8
    float* p_abn2 = p_pos  + 1024 * 8;     // 2048*16
    float* p_bn2  = p_abn2 + 2048 * 16;    // 256*128
    float* p_bn3  = p_bn2  + 256 * 128;    // 256*128
    float* ssb    = p_bn3  + 256 * 128;
    float* ss_bn1 = ssb;         // [scale 64][shift 64]
    float* ss_pos = ssb + 128;   // [scale 4][shift 4]
    float* ss_a1  = ssb + 136;   // 128
    float* ss_a2  = ssb + 264;   // 16
    float* ss_bn2 = ssb + 280;   // 128
    float* ss_bn3 = ssb + 408;   // 128
    // p_abn1 (2048*128 = 1 MB) aliases buf_t1: consumed by its reducer BEFORE
    // k_edge_t1 writes t1 into the same region.
    float* p_abn1 = buf_t1;

    float* buf_out = buf_asrc;   // reuse after a_src consumed

    // 1) y1 = x @ W_in^T
    k_gemm_tile<<<1024, 256, 0, stream>>>(x, W_in, nullptr, nullptr, buf_y);
    // 2-3) bn1 stats
    k_colstats<<<256, 256, 0, stream>>>(buf_y, p_bn1);
    k_reduce_bn<<<1, 1024, 0, stream>>>(p_bn1, 256, 64, 64, 1.f / N_, bn1g, bn1b, ss_bn1);
    // 4) h = relu(bn1(y1)); a_src/a_dst/hW
    k_gemm3_tile<<<1024, 256, 0, stream>>>(buf_y, ss_bn1, srcw, srcb, dstw, dstb, linw, linb,
                                           buf_asrc, buf_adst, buf_hw);
    // 5-6) pos-BN stats
    k_pos_stats<<<1024, 256, 0, stream>>>(pos, src, pw1, pb1, p_pos);
    k_reduce_bn<<<1, 1024, 0, stream>>>(p_pos, 1024, 4, 3, 1.f / E_, pbg, pbb, ss_pos);
    // 7-8) attn_bn1 stats (group-per-node, coalesced gathers)
    k_abn1_stats<<<2048, 256, 0, stream>>>(pos, src, buf_asrc, buf_adst,
                                           pw1, pb1, ss_pos, pw2, pb2, p_abn1);
    k_reduce_bn<<<1, 1024, 0, stream>>>(p_abn1, 2048, 64, 64, 1.f / E_, a1g, a1b, ss_a1);
    // 9-10) t1 = relu(abn1(a)) @ attn_w1^T + b1 ; abn2 stats
    k_edge_t1<<<2048, 256, 0, stream>>>(pos, src, buf_asrc, buf_adst,
                                        pw1, pb1, ss_pos, pw2, pb2,
                                        ss_a1, aw1, ab1, buf_t1, p_abn2);
    k_reduce_bn<<<1, 1024, 0, stream>>>(p_abn2, 2048, 8, 8, 1.f / E_, a2g, a2b, ss_a2);
    // 11) softmax + weighted aggregate -> out [N,64]
    k_node_aggr<<<4096, 256, 0, stream>>>(pos, src, buf_t1, ss_a2, aw2, ab2,
                                          buf_hw, ss_pos, pw1, pb1, pw2, pb2, buf_out);
    // 12-13) bn2 stats
    k_colstats<<<256, 256, 0, stream>>>(buf_out, p_bn2);
    k_reduce_bn<<<1, 1024, 0, stream>>>(p_bn2, 256, 64, 64, 1.f / N_, bn2g, bn2b, ss_bn2);
    // 14) y3 = relu(bn2(out)) @ W_out^T
    k_gemm_tile<<<1024, 256, 0, stream>>>(buf_out, W_out, nullptr, ss_bn2, buf_y);
    // 15-16) bn3 stats
    k_colstats<<<256, 256, 0, stream>>>(buf_y, p_bn3);
    k_reduce_bn<<<1, 1024, 0, stream>>>(p_bn3, 256, 64, 64, 1.f / N_, bn3g, bn3b, ss_bn3);
    // 17) out = relu(bn3(y3) + x)
    k_final<<<(N_ * C_ / 4) / 256, 256, 0, stream>>>(buf_y, ss_bn3, x, outp);

    (void)in_sizes; (void)n_in; (void)out_size; (void)ws_size;
}

// Round 8
// 354.430 us; speedup vs baseline: 2.5240x; 1.1041x over previous
//
#include <hip/hip_runtime.h>
#include <cstddef>

constexpr int N_ = 65536;
constexpr int K_ = 16;
constexpr int E_ = N_ * K_;      // 1048576
constexpr int C_ = 64;
#define EPS_ 1e-5f
#define SW 68   // LDS row stride (words) for GEMM tiles

typedef unsigned int uint_t;

// bf16 helpers (RNE pack, cheap unpack)
__device__ __forceinline__ uint_t bf16_rne(float f) {
    uint_t u = __float_as_uint(f);
    return (u + 0x7fffu + ((u >> 16) & 1u)) >> 16;
}
__device__ __forceinline__ float bf16_lo(uint_t p) { return __uint_as_float(p << 16); }
__device__ __forceinline__ float bf16_hi(uint_t p) { return __uint_as_float(p & 0xffff0000u); }

// ---------------------------------------------------------------------------
// BN stats reducer (R2: parallel, 4x unrolled, LDS tree).
__global__ __launch_bounds__(1024)
void k_reduce_bn(const float* __restrict__ part, int P, int nchp, int nch,
                 float invM, const float* __restrict__ g,
                 const float* __restrict__ b, float* __restrict__ ss)
{
    int t = threadIdx.x;
    int c = t & (nchp - 1);
    int r = t / nchp;
    int R = 1024 / nchp;
    int stride = 2 * nchp;
    float s0 = 0.f, s1 = 0.f, s2 = 0.f, s3 = 0.f;
    float q0 = 0.f, q1 = 0.f, q2 = 0.f, q3 = 0.f;
    int p = r;
    for (; p + 3 * R < P; p += 4 * R) {
        int i0 = p * stride + c;
        int i1 = (p + R) * stride + c;
        int i2 = (p + 2 * R) * stride + c;
        int i3 = (p + 3 * R) * stride + c;
        s0 += part[i0];        s1 += part[i1];
        s2 += part[i2];        s3 += part[i3];
        q0 += part[i0 + nchp]; q1 += part[i1 + nchp];
        q2 += part[i2 + nchp]; q3 += part[i3 + nchp];
    }
    for (; p < P; p += R) {
        s0 += part[p * stride + c];
        q0 += part[p * stride + nchp + c];
    }
    float s = (s0 + s1) + (s2 + s3);
    float q = (q0 + q1) + (q2 + q3);
    __shared__ float reds[1024], redq[1024];
    reds[t] = s; redq[t] = q;
    __syncthreads();
    for (int off = 512; off >= nchp; off >>= 1) {
        if (t < off) { reds[t] += reds[t + off]; redq[t] += redq[t + off]; }
        __syncthreads();
    }
    if (t < nch) {
        float mean = reds[t] * invM;
        float var  = fmaxf(redq[t] * invM - mean * mean, 0.f);
        float sc = g[t] * rsqrtf(var + EPS_);
        ss[t] = sc;
        ss[nchp + t] = b[t] - mean * sc;
    }
}

// ---------------------------------------------------------------------------
// Column stats over [65536 x 64] row-major buffer. Grid 256 blocks x 256 thr.
__global__ __launch_bounds__(256)
void k_colstats(const float* __restrict__ buf, float* __restrict__ part)
{
    int t = threadIdx.x, c = t & 63, rg = t >> 6;
    float s = 0.f, q = 0.f;
    int base = blockIdx.x * 256 + rg * 64;
    for (int i = 0; i < 64; ++i) {
        float v = buf[(size_t)(base + i) * 64 + c];
        s += v; q = fmaf(v, v, q);
    }
    __shared__ float red[2][256];
    red[0][t] = s; red[1][t] = q;
    __syncthreads();
    if (t < 64) {
        float S = red[0][t] + red[0][t + 64] + red[0][t + 128] + red[0][t + 192];
        float Q = red[1][t] + red[1][t + 64] + red[1][t + 128] + red[1][t + 192];
        part[blockIdx.x * 128 + t]      = S;
        part[blockIdx.x * 128 + 64 + t] = Q;
    }
}

// ---------------------------------------------------------------------------
// R5 GEMM structure (LDS-tiled, coalesced).
__device__ __forceinline__ void stage_x(const float* __restrict__ in,
                                        const float* __restrict__ ss,
                                        float* __restrict__ Xs, int row0, int t)
{
#pragma unroll
    for (int it = 0; it < 4; ++it) {
        int m = t + 256 * it;
        int r = m >> 4, j = m & 15;
        float4 v = ((const float4*)in)[(size_t)(row0 + r) * 16 + j];
        if (ss) {
            float4 sc = ((const float4*)ss)[j];
            float4 sh = ((const float4*)(ss + 64))[j];
            v.x = fmaxf(fmaf(v.x, sc.x, sh.x), 0.f);
            v.y = fmaxf(fmaf(v.y, sc.y, sh.y), 0.f);
            v.z = fmaxf(fmaf(v.z, sc.z, sh.z), 0.f);
            v.w = fmaxf(fmaf(v.w, sc.w, sh.w), 0.f);
        }
        *(float4*)&Xs[r * SW + 4 * j] = v;
    }
}

__device__ __forceinline__ void stage_w(const float* __restrict__ W,
                                        float* __restrict__ Ws, int t)
{
#pragma unroll
    for (int it = 0; it < 4; ++it) {
        int m = t + 256 * it;
        int r = m >> 4, j = m & 15;
        *(float4*)&Ws[r * SW + 4 * j] = ((const float4*)W)[m];
    }
}

__device__ __forceinline__ void compute_tile(const float* __restrict__ Xs,
                                             const float* __restrict__ Ws,
                                             int tx, int ty, float acc[4][4])
{
#pragma unroll
    for (int r = 0; r < 4; ++r)
#pragma unroll
        for (int c = 0; c < 4; ++c) acc[r][c] = 0.f;
    for (int kc = 0; kc < 16; ++kc) {
        float4 xf[4], wf[4];
#pragma unroll
        for (int r = 0; r < 4; ++r)
            xf[r] = *(const float4*)&Xs[(tx + 16 * r) * SW + 4 * kc];
#pragma unroll
        for (int c = 0; c < 4; ++c)
            wf[c] = *(const float4*)&Ws[(ty + 16 * c) * SW + 4 * kc];
#pragma unroll
        for (int r = 0; r < 4; ++r)
#pragma unroll
            for (int c = 0; c < 4; ++c) {
                acc[r][c] = fmaf(xf[r].x, wf[c].x, acc[r][c]);
                acc[r][c] = fmaf(xf[r].y, wf[c].y, acc[r][c]);
                acc[r][c] = fmaf(xf[r].z, wf[c].z, acc[r][c]);
                acc[r][c] = fmaf(xf[r].w, wf[c].w, acc[r][c]);
            }
    }
}

__device__ __forceinline__ void write_tile(float* __restrict__ buf, int tx, int ty,
                                           const float acc[4][4],
                                           const float* __restrict__ bias,
                                           float* __restrict__ out, int row0, int t)
{
    __syncthreads();
#pragma unroll
    for (int r = 0; r < 4; ++r)
#pragma unroll
        for (int c = 0; c < 4; ++c)
            buf[(tx + 16 * r) * SW + ty + 16 * c] = acc[r][c];
    __syncthreads();
#pragma unroll
    for (int it = 0; it < 4; ++it) {
        int m = t + 256 * it;
        int r = m >> 4, j = m & 15;
        float4 v = *(const float4*)&buf[r * SW + 4 * j];
        if (bias) {
            float4 bv = ((const float4*)bias)[j];
            v.x += bv.x; v.y += bv.y; v.z += bv.z; v.w += bv.w;
        }
        ((float4*)out)[(size_t)(row0 + r) * 16 + j] = v;
    }
    __syncthreads();
}

// bf16 variant: rounds to bf16 (RNE) and stores 8B/lane coalesced.
__device__ __forceinline__ void write_tile_bf16(float* __restrict__ buf, int tx, int ty,
                                                const float acc[4][4],
                                                const float* __restrict__ bias,
                                                unsigned short* __restrict__ out,
                                                int row0, int t)
{
    __syncthreads();
#pragma unroll
    for (int r = 0; r < 4; ++r)
#pragma unroll
        for (int c = 0; c < 4; ++c)
            buf[(tx + 16 * r) * SW + ty + 16 * c] = acc[r][c];
    __syncthreads();
#pragma unroll
    for (int it = 0; it < 4; ++it) {
        int m = t + 256 * it;
        int r = m >> 4, j = m & 15;
        float4 v = *(const float4*)&buf[r * SW + 4 * j];
        if (bias) {
            float4 bv = ((const float4*)bias)[j];
            v.x += bv.x; v.y += bv.y; v.z += bv.z; v.w += bv.w;
        }
        uint2 o;
        o.x = bf16_rne(v.x) | (bf16_rne(v.y) << 16);
        o.y = bf16_rne(v.z) | (bf16_rne(v.w) << 16);
        ((uint2*)out)[(size_t)(row0 + r) * 16 + j] = o;
    }
    __syncthreads();
}

__global__ __launch_bounds__(256)
void k_gemm_tile(const float* __restrict__ in, const float* __restrict__ W,
                 const float* __restrict__ bias, const float* __restrict__ ss,
                 float* __restrict__ out)
{
    __shared__ float Xs[64 * SW];
    __shared__ float Ws[64 * SW];
    int t = threadIdx.x, tx = t & 15, ty = t >> 4;
    int row0 = blockIdx.x * 64;
    stage_x(in, ss, Xs, row0, t);
    stage_w(W, Ws, t);
    __syncthreads();
    float acc[4][4];
    compute_tile(Xs, Ws, tx, ty, acc);
    write_tile(Ws, tx, ty, acc, bias, out, row0, t);
}

// h = relu(bn1(y)); asrc16 = bf16(h@Wa^T+ba); adst = h@Wb^T+bb (f32);
// hw16 = bf16(h@Wc^T+bc)
__global__ __launch_bounds__(256)
void k_gemm3_tile(const float* __restrict__ y, const float* __restrict__ ss,
                  const float* __restrict__ Wa, const float* __restrict__ ba,
                  const float* __restrict__ Wb, const float* __restrict__ bb,
                  const float* __restrict__ Wc, const float* __restrict__ bc,
                  unsigned short* __restrict__ oa16, float* __restrict__ ob,
                  unsigned short* __restrict__ oc16)
{
    __shared__ float Xs[64 * SW];
    __shared__ float Ws[64 * SW];
    int t = threadIdx.x, tx = t & 15, ty = t >> 4;
    int row0 = blockIdx.x * 64;
    stage_x(y, ss, Xs, row0, t);
    stage_w(Wa, Ws, t);
    __syncthreads();
    float acc[4][4];
    compute_tile(Xs, Ws, tx, ty, acc);
    write_tile_bf16(Ws, tx, ty, acc, ba, oa16, row0, t);
    stage_w(Wb, Ws, t);
    __syncthreads();
    compute_tile(Xs, Ws, tx, ty, acc);
    write_tile(Ws, tx, ty, acc, bb, ob, row0, t);
    stage_w(Wc, Ws, t);
    __syncthreads();
    compute_tile(Xs, Ws, tx, ty, acc);
    write_tile_bf16(Ws, tx, ty, acc, bc, oc16, row0, t);
}

// ---------------------------------------------------------------------------
// Stats of u = rel @ pos_w1^T + pos_b1 over E edges (3 channels, pad 4).
__global__ __launch_bounds__(256)
void k_pos_stats(const float* __restrict__ pos, const int* __restrict__ src,
                 const float* __restrict__ pw1, const float* __restrict__ pb1,
                 float* __restrict__ part)
{
    float s0 = 0, s1 = 0, s2 = 0, q0 = 0, q1 = 0, q2 = 0;
    int tid = blockIdx.x * 256 + threadIdx.x;
    for (int e = tid; e < E_; e += 1024 * 256) {
        int si = src[e], di = e >> 4;
        float rx = pos[3 * si + 0] - pos[3 * di + 0];
        float ry = pos[3 * si + 1] - pos[3 * di + 1];
        float rz = pos[3 * si + 2] - pos[3 * di + 2];
        float u0 = fmaf(rx, pw1[0], fmaf(ry, pw1[1], fmaf(rz, pw1[2], pb1[0])));
        float u1 = fmaf(rx, pw1[3], fmaf(ry, pw1[4], fmaf(rz, pw1[5], pb1[1])));
        float u2 = fmaf(rx, pw1[6], fmaf(ry, pw1[7], fmaf(rz, pw1[8], pb1[2])));
        s0 += u0; q0 = fmaf(u0, u0, q0);
        s1 += u1; q1 = fmaf(u1, u1, q1);
        s2 += u2; q2 = fmaf(u2, u2, q2);
    }
#pragma unroll
    for (int m = 1; m < 64; m <<= 1) {
        s0 += __shfl_xor(s0, m, 64); s1 += __shfl_xor(s1, m, 64); s2 += __shfl_xor(s2, m, 64);
        q0 += __shfl_xor(q0, m, 64); q1 += __shfl_xor(q1, m, 64); q2 += __shfl_xor(q2, m, 64);
    }
    __shared__ float red[4][8];
    int wv = threadIdx.x >> 6, ln = threadIdx.x & 63;
    if (ln == 0) {
        red[wv][0] = s0; red[wv][1] = s1; red[wv][2] = s2; red[wv][3] = 0.f;
        red[wv][4] = q0; red[wv][5] = q1; red[wv][6] = q2; red[wv][7] = 0.f;
    }
    __syncthreads();
    if (threadIdx.x < 8)
        part[blockIdx.x * 8 + threadIdx.x] =
            red[0][threadIdx.x] + red[1][threadIdx.x] + red[2][threadIdx.x] + red[3][threadIdx.x];
}

// ---------------------------------------------------------------------------
// R8 edge kernels: group-per-node + per-lane d-precompute (lane l computes its
// own edge's d once; k-loop broadcasts via 3 group shuffles) + bf16 asrc/hw.

// Stats of a = bf16(a_src)[src]-a_dst[dst]+delta. Grid 2048 x 256.
__global__ __launch_bounds__(256)
void k_abn1_stats(const float* __restrict__ pos, const int* __restrict__ src,
                  const unsigned short* __restrict__ asrc16,
                  const float* __restrict__ adst,
                  const float* __restrict__ pw1, const float* __restrict__ pb1,
                  const float* __restrict__ sspos, const float* __restrict__ pw2,
                  const float* __restrict__ pb2, float* __restrict__ part)
{
    int t = threadIdx.x;
    int l = t & 15, g = t >> 4, wv = t >> 6;
    int c0 = 4 * l;
    float4 p0 = *(const float4*)(pw2 + 12 * l);
    float4 p1 = *(const float4*)(pw2 + 12 * l + 4);
    float4 p2 = *(const float4*)(pw2 + 12 * l + 8);
    float4 pb = *(const float4*)(pb2 + c0);
    float sa0 = 0, sa1 = 0, sa2 = 0, sa3 = 0;
    float qa0 = 0, qa1 = 0, qa2 = 0, qa3 = 0;
#pragma unroll
    for (int nn = 0; nn < 2; ++nn) {
        int n = blockIdx.x * 32 + nn * 16 + g;
        float4 dv = *(const float4*)(adst + (size_t)n * 64 + c0);
        float pnx = pos[3 * n + 0], pny = pos[3 * n + 1], pnz = pos[3 * n + 2];
        int si_l = src[n * 16 + l];
        float rx = pos[3 * si_l + 0] - pnx;
        float ry = pos[3 * si_l + 1] - pny;
        float rz = pos[3 * si_l + 2] - pnz;
        float u0 = fmaf(rx, pw1[0], fmaf(ry, pw1[1], fmaf(rz, pw1[2], pb1[0])));
        float u1 = fmaf(rx, pw1[3], fmaf(ry, pw1[4], fmaf(rz, pw1[5], pb1[1])));
        float u2 = fmaf(rx, pw1[6], fmaf(ry, pw1[7], fmaf(rz, pw1[8], pb1[2])));
        float dl0 = fmaxf(fmaf(u0, sspos[0], sspos[4]), 0.f);
        float dl1 = fmaxf(fmaf(u1, sspos[1], sspos[5]), 0.f);
        float dl2 = fmaxf(fmaf(u2, sspos[2], sspos[6]), 0.f);
        for (int k = 0; k < 16; ++k) {
            int si = __shfl(si_l, k, 16);
            float d0 = __shfl(dl0, k, 16);
            float d1 = __shfl(dl1, k, 16);
            float d2 = __shfl(dl2, k, 16);
            uint2 raw = ((const uint2*)asrc16)[(size_t)si * 16 + l];
            float avx = bf16_lo(raw.x), avy = bf16_hi(raw.x);
            float avz = bf16_lo(raw.y), avw = bf16_hi(raw.y);
            float del0 = fmaf(d0, p0.x, fmaf(d1, p0.y, fmaf(d2, p0.z, pb.x)));
            float del1 = fmaf(d0, p0.w, fmaf(d1, p1.x, fmaf(d2, p1.y, pb.y)));
            float del2 = fmaf(d0, p1.z, fmaf(d1, p1.w, fmaf(d2, p2.x, pb.z)));
            float del3 = fmaf(d0, p2.y, fmaf(d1, p2.z, fmaf(d2, p2.w, pb.w)));
            float a0 = avx - dv.x + del0;
            float a1 = avy - dv.y + del1;
            float a2 = avz - dv.z + del2;
            float a3 = avw - dv.w + del3;
            sa0 += a0; qa0 = fmaf(a0, a0, qa0);
            sa1 += a1; qa1 = fmaf(a1, a1, qa1);
            sa2 += a2; qa2 = fmaf(a2, a2, qa2);
            sa3 += a3; qa3 = fmaf(a3, a3, qa3);
        }
    }
#pragma unroll
    for (int m = 16; m <= 32; m <<= 1) {
        sa0 += __shfl_xor(sa0, m, 64); sa1 += __shfl_xor(sa1, m, 64);
        sa2 += __shfl_xor(sa2, m, 64); sa3 += __shfl_xor(sa3, m, 64);
        qa0 += __shfl_xor(qa0, m, 64); qa1 += __shfl_xor(qa1, m, 64);
        qa2 += __shfl_xor(qa2, m, 64); qa3 += __shfl_xor(qa3, m, 64);
    }
    __shared__ float red[4][128];
    if ((t & 63) < 16) {
        red[wv][c0 + 0] = sa0; red[wv][c0 + 1] = sa1;
        red[wv][c0 + 2] = sa2; red[wv][c0 + 3] = sa3;
        red[wv][64 + c0 + 0] = qa0; red[wv][64 + c0 + 1] = qa1;
        red[wv][64 + c0 + 2] = qa2; red[wv][64 + c0 + 3] = qa3;
    }
    __syncthreads();
    if (t < 128)
        part[blockIdx.x * 128 + t] = red[0][t] + red[1][t] + red[2][t] + red[3][t];
}

// ---------------------------------------------------------------------------
// t1 = relu(abn1(a)) @ attn_w1^T + attn_b1; abn2 stats. Grid 2048 x 256.
__global__ __launch_bounds__(256)
void k_edge_t1(const float* __restrict__ pos, const int* __restrict__ src,
               const unsigned short* __restrict__ asrc16,
               const float* __restrict__ adst,
               const float* __restrict__ pw1, const float* __restrict__ pb1,
               const float* __restrict__ sspos, const float* __restrict__ pw2,
               const float* __restrict__ pb2, const float* __restrict__ ssa1,
               const float* __restrict__ aw1, const float* __restrict__ ab1,
               float* __restrict__ t1, float* __restrict__ part)
{
    int t = threadIdx.x;
    int l = t & 15, g = t >> 4, wv = t >> 6;
    int c0 = 4 * l;
    int ch = 4 * (l & 1) + 2 * ((l >> 1) & 1) + ((l >> 2) & 1);
    float abv = ab1[ch];
    float4 p0 = *(const float4*)(pw2 + 12 * l);
    float4 p1 = *(const float4*)(pw2 + 12 * l + 4);
    float4 p2 = *(const float4*)(pw2 + 12 * l + 8);
    float4 pb = *(const float4*)(pb2 + c0);
    float4 sc = *(const float4*)(ssa1 + c0);
    float4 sh = *(const float4*)(ssa1 + 64 + c0);
    float4 w1[8];
#pragma unroll
    for (int jj = 0; jj < 8; ++jj) w1[jj] = *(const float4*)(aw1 + jj * 64 + c0);
    float sse = 0.f, ssq = 0.f;
#pragma unroll
    for (int nn = 0; nn < 2; ++nn) {
        int n = blockIdx.x * 32 + nn * 16 + g;
        float4 dv = *(const float4*)(adst + (size_t)n * 64 + c0);
        float pnx = pos[3 * n + 0], pny = pos[3 * n + 1], pnz = pos[3 * n + 2];
        int si_l = src[n * 16 + l];
        float rx = pos[3 * si_l + 0] - pnx;
        float ry = pos[3 * si_l + 1] - pny;
        float rz = pos[3 * si_l + 2] - pnz;
        float u0 = fmaf(rx, pw1[0], fmaf(ry, pw1[1], fmaf(rz, pw1[2], pb1[0])));
        float u1 = fmaf(rx, pw1[3], fmaf(ry, pw1[4], fmaf(rz, pw1[5], pb1[1])));
        float u2 = fmaf(rx, pw1[6], fmaf(ry, pw1[7], fmaf(rz, pw1[8], pb1[2])));
        float dl0 = fmaxf(fmaf(u0, sspos[0], sspos[4]), 0.f);
        float dl1 = fmaxf(fmaf(u1, sspos[1], sspos[5]), 0.f);
        float dl2 = fmaxf(fmaf(u2, sspos[2], sspos[6]), 0.f);
        for (int k = 0; k < 16; ++k) {
            int si = __shfl(si_l, k, 16);
            float d0 = __shfl(dl0, k, 16);
            float d1 = __shfl(dl1, k, 16);
            float d2 = __shfl(dl2, k, 16);
            uint2 raw = ((const uint2*)asrc16)[(size_t)si * 16 + l];
            float avx = bf16_lo(raw.x), avy = bf16_hi(raw.x);
            float avz = bf16_lo(raw.y), avw = bf16_hi(raw.y);
            float del0 = fmaf(d0, p0.x, fmaf(d1, p0.y, fmaf(d2, p0.z, pb.x)));
            float del1 = fmaf(d0, p0.w, fmaf(d1, p1.x, fmaf(d2, p1.y, pb.y)));
            float del2 = fmaf(d0, p1.z, fmaf(d1, p1.w, fmaf(d2, p2.x, pb.z)));
            float del3 = fmaf(d0, p2.y, fmaf(d1, p2.z, fmaf(d2, p2.w, pb.w)));
            float an0 = fmaxf(fmaf(avx - dv.x + del0, sc.x, sh.x), 0.f);
            float an1 = fmaxf(fmaf(avy - dv.y + del1, sc.y, sh.y), 0.f);
            float an2 = fmaxf(fmaf(avz - dv.z + del2, sc.z, sh.z), 0.f);
            float an3 = fmaxf(fmaf(avw - dv.w + del3, sc.w, sh.w), 0.f);
            float tp[8];
#pragma unroll
            for (int jj = 0; jj < 8; ++jj)
                tp[jj] = fmaf(an0, w1[jj].x, fmaf(an1, w1[jj].y,
                         fmaf(an2, w1[jj].z, an3 * w1[jj].w)));
            // reduce-scatter: 8 -> 4 -> 2 -> 1 values
            float s4[4];
#pragma unroll
            for (int j = 0; j < 4; ++j) {
                float send = (l & 1) ? tp[j] : tp[j + 4];
                float recv = __shfl_xor(send, 1, 64);
                s4[j] = ((l & 1) ? tp[j + 4] : tp[j]) + recv;
            }
            float s2[2];
#pragma unroll
            for (int j = 0; j < 2; ++j) {
                float send = (l & 2) ? s4[j] : s4[j + 2];
                float recv = __shfl_xor(send, 2, 64);
                s2[j] = ((l & 2) ? s4[j + 2] : s4[j]) + recv;
            }
            float send = (l & 4) ? s2[0] : s2[1];
            float recv = __shfl_xor(send, 4, 64);
            float s1 = ((l & 4) ? s2[1] : s2[0]) + recv;
            s1 += __shfl_xor(s1, 8, 64);
            float o = s1 + abv;
            if (l < 8) t1[(size_t)(n * 16 + k) * 8 + ch] = o;
            sse += o; ssq = fmaf(o, o, ssq);
        }
    }
#pragma unroll
    for (int m = 16; m <= 32; m <<= 1) {
        sse += __shfl_xor(sse, m, 64);
        ssq += __shfl_xor(ssq, m, 64);
    }
    __shared__ float red[4][16];
    if ((t & 63) < 8) { red[wv][ch] = sse; red[wv][8 + ch] = ssq; }
    __syncthreads();
    if (t < 16)
        part[blockIdx.x * 16 + t] = red[0][t] + red[1][t] + red[2][t] + red[3][t];
}

// ---------------------------------------------------------------------------
// Softmax + weighted aggregate, group-per-node. Grid 4096 x 256 (16 nodes/blk).
__global__ __launch_bounds__(256)
void k_node_aggr(const float* __restrict__ pos, const int* __restrict__ src,
                 const float* __restrict__ t1, const float* __restrict__ ssa2,
                 const float* __restrict__ aw2, const float* __restrict__ ab2,
                 const unsigned short* __restrict__ hw16,
                 const float* __restrict__ sspos,
                 const float* __restrict__ pw1, const float* __restrict__ pb1,
                 const float* __restrict__ pw2, const float* __restrict__ pb2,
                 float* __restrict__ out)
{
    __shared__ float alds[16][196];   // [group][k*12 + ch8]
    int t = threadIdx.x, l = t & 15, g = t >> 4;
    int c0 = 4 * l;
    float4 p0 = *(const float4*)(pw2 + 12 * l);
    float4 p1 = *(const float4*)(pw2 + 12 * l + 4);
    float4 p2 = *(const float4*)(pw2 + 12 * l + 8);
    float4 pb = *(const float4*)(pb2 + c0);
    int alof = (l & 1) * 4;
    int n = blockIdx.x * 16 + g;
    int e = n * 16 + l;
    // ---- phase A: per-edge attention logits + softmax over the group
    const float4* t4 = (const float4*)(t1 + (size_t)e * 8);
    float4 ta = t4[0], tb = t4[1];
    float tv[8] = {ta.x, ta.y, ta.z, ta.w, tb.x, tb.y, tb.z, tb.w};
    float tn[8];
#pragma unroll
    for (int j = 0; j < 8; ++j)
        tn[j] = fmaxf(fmaf(tv[j], ssa2[j], ssa2[8 + j]), 0.f);
    float al[8];
#pragma unroll
    for (int j = 0; j < 8; ++j) {
        float acc = ab2[j];
#pragma unroll
        for (int i = 0; i < 8; ++i) acc = fmaf(tn[i], aw2[j * 8 + i], acc);
        float m = acc;
#pragma unroll
        for (int msk = 1; msk < 16; msk <<= 1) m = fmaxf(m, __shfl_xor(m, msk, 64));
        float ex = __expf(acc - m);
        float sm = ex;
#pragma unroll
        for (int msk = 1; msk < 16; msk <<= 1) sm += __shfl_xor(sm, msk, 64);
        al[j] = ex / sm;
    }
    *(float4*)&alds[g][l * 12]     = make_float4(al[0], al[1], al[2], al[3]);
    *(float4*)&alds[g][l * 12 + 4] = make_float4(al[4], al[5], al[6], al[7]);
    int silane = src[e];
    float pnx = pos[3 * n + 0], pny = pos[3 * n + 1], pnz = pos[3 * n + 2];
    // own-edge d
    float rx = pos[3 * silane + 0] - pnx;
    float ry = pos[3 * silane + 1] - pny;
    float rz = pos[3 * silane + 2] - pnz;
    float u0 = fmaf(rx, pw1[0], fmaf(ry, pw1[1], fmaf(rz, pw1[2], pb1[0])));
    float u1 = fmaf(rx, pw1[3], fmaf(ry, pw1[4], fmaf(rz, pw1[5], pb1[1])));
    float u2 = fmaf(rx, pw1[6], fmaf(ry, pw1[7], fmaf(rz, pw1[8], pb1[2])));
    float dl0 = fmaxf(fmaf(u0, sspos[0], sspos[4]), 0.f);
    float dl1 = fmaxf(fmaf(u1, sspos[1], sspos[5]), 0.f);
    float dl2 = fmaxf(fmaf(u2, sspos[2], sspos[6]), 0.f);
    // ---- phase B: accumulate own 4 channels over the node's 16 edges
    float a0 = 0.f, a1 = 0.f, a2 = 0.f, a3 = 0.f;
#pragma unroll 4
    for (int k = 0; k < 16; ++k) {
        int sk = __shfl(silane, k, 16);
        float d0 = __shfl(dl0, k, 16);
        float d1 = __shfl(dl1, k, 16);
        float d2 = __shfl(dl2, k, 16);
        uint2 raw = ((const uint2*)hw16)[(size_t)sk * 16 + l];
        float hvx = bf16_lo(raw.x), hvy = bf16_hi(raw.x);
        float hvz = bf16_lo(raw.y), hvw = bf16_hi(raw.y);
        float4 alv = *(const float4*)&alds[g][k * 12 + alof];
        float del0 = fmaf(d0, p0.x, fmaf(d1, p0.y, fmaf(d2, p0.z, pb.x)));
        float del1 = fmaf(d0, p0.w, fmaf(d1, p1.x, fmaf(d2, p1.y, pb.y)));
        float del2 = fmaf(d0, p1.z, fmaf(d1, p1.w, fmaf(d2, p2.x, pb.z)));
        float del3 = fmaf(d0, p2.y, fmaf(d1, p2.z, fmaf(d2, p2.w, pb.w)));
        a0 = fmaf(alv.x, hvx + del0, a0);
        a1 = fmaf(alv.y, hvy + del1, a1);
        a2 = fmaf(alv.z, hvz + del2, a2);
        a3 = fmaf(alv.w, hvw + del3, a3);
    }
    *(float4*)(out + (size_t)n * 64 + c0) = make_float4(a0, a1, a2, a3);
}

// ---------------------------------------------------------------------------
// out = relu(bn3(y3) + x_skip)
__global__ __launch_bounds__(256)
void k_final(const float* __restrict__ y3, const float* __restrict__ ss3,
             const float* __restrict__ x, float* __restrict__ out)
{
    int i = blockIdx.x * 256 + threadIdx.x;   // float4 index
    int c4 = i & 15;
    float4 sc = ((const float4*)ss3)[c4];
    float4 sh = ((const float4*)(ss3 + 64))[c4];
    float4 v  = ((const float4*)y3)[i];
    float4 xs = ((const float4*)x)[i];
    float4 o;
    o.x = fmaxf(fmaf(v.x, sc.x, sh.x) + xs.x, 0.f);
    o.y = fmaxf(fmaf(v.y, sc.y, sh.y) + xs.y, 0.f);
    o.z = fmaxf(fmaf(v.z, sc.z, sh.z) + xs.z, 0.f);
    o.w = fmaxf(fmaf(v.w, sc.w, sh.w) + xs.w, 0.f);
    ((float4*)out)[i] = o;
}

// ---------------------------------------------------------------------------
extern "C" void kernel_launch(void* const* d_in, const int* in_sizes, int n_in,
                              void* d_out, int out_size, void* d_ws, size_t ws_size,
                              hipStream_t stream)
{
    const float* x    = (const float*)d_in[0];
    const float* pos  = (const float*)d_in[1];
    const int*   src  = (const int*)d_in[2];           // edge_index row 0
    const float* W_in = (const float*)d_in[3];
    const float* W_out= (const float*)d_in[4];
    const float* pw1  = (const float*)d_in[5];
    const float* pb1  = (const float*)d_in[6];
    const float* pbg  = (const float*)d_in[7];
    const float* pbb  = (const float*)d_in[8];
    const float* pw2  = (const float*)d_in[9];
    const float* pb2  = (const float*)d_in[10];
    const float* a1g  = (const float*)d_in[11];
    const float* a1b  = (const float*)d_in[12];
    const float* aw1  = (const float*)d_in[13];
    const float* ab1  = (const float*)d_in[14];
    const float* a2g  = (const float*)d_in[15];
    const float* a2b  = (const float*)d_in[16];
    const float* aw2  = (const float*)d_in[17];
    const float* ab2  = (const float*)d_in[18];
    const float* linw = (const float*)d_in[19];
    const float* linb = (const float*)d_in[20];
    const float* srcw = (const float*)d_in[21];
    const float* srcb = (const float*)d_in[22];
    const float* dstw = (const float*)d_in[23];
    const float* dstb = (const float*)d_in[24];
    const float* bn1g = (const float*)d_in[25];
    const float* bn1b = (const float*)d_in[26];
    const float* bn2g = (const float*)d_in[27];
    const float* bn2b = (const float*)d_in[28];
    const float* bn3g = (const float*)d_in[29];
    const float* bn3b = (const float*)d_in[30];
    float* outp = (float*)d_out;

    float* ws = (float*)d_ws;
    const size_t NC = (size_t)N_ * C_;
    float* buf_y     = ws;                       // y1, later y3
    float* buf_adst  = ws + NC;                  // a_dst f32; later reused as out
    unsigned short* asrc16 = (unsigned short*)(ws + 2 * NC);       // NC/2 floats
    unsigned short* hw16   = (unsigned short*)(ws + 2 * NC + NC / 2);
    float* buf_t1    = ws + 3 * NC;              // [E,8] f32
    float* pbase     = ws + 3 * NC + (size_t)E_ * 8;
    float* p_bn1  = pbase;                 // 256*128
    float* p_pos  = p_bn1  + 256 * 128;    // 1024*8
    float* p_abn2 = p_pos  + 1024 * 8;     // 2048*16
    float* p_bn2  = p_abn2 + 2048 * 16;    // 256*128
    float* p_bn3  = p_bn2  + 256 * 128;    // 256*128
    float* ssb    = p_bn3  + 256 * 128;
    float* ss_bn1 = ssb;         // [scale 64][shift 64]
    float* ss_pos = ssb + 128;   // [scale 4][shift 4]
    float* ss_a1  = ssb + 136;   // 128
    float* ss_a2  = ssb + 264;   // 16
    float* ss_bn2 = ssb + 280;   // 128
    float* ss_bn3 = ssb + 408;   // 128
    // p_abn1 (2048*128 = 1 MB) aliases buf_t1: consumed by its reducer BEFORE
    // k_edge_t1 writes t1 into the same region.
    float* p_abn1 = buf_t1;
    // buf_out aliases buf_adst: adst last read by k_edge_t1 (step 9); node_aggr
    // writes out afterwards (step 11).
    float* buf_out = buf_adst;

    // 1) y1 = x @ W_in^T
    k_gemm_tile<<<1024, 256, 0, stream>>>(x, W_in, nullptr, nullptr, buf_y);
    // 2-3) bn1 stats
    k_colstats<<<256, 256, 0, stream>>>(buf_y, p_bn1);
    k_reduce_bn<<<1, 1024, 0, stream>>>(p_bn1, 256, 64, 64, 1.f / N_, bn1g, bn1b, ss_bn1);
    // 4) h = relu(bn1(y1)); asrc16 (bf16) / adst (f32) / hw16 (bf16)
    k_gemm3_tile<<<1024, 256, 0, stream>>>(buf_y, ss_bn1, srcw, srcb, dstw, dstb, linw, linb,
                                           asrc16, buf_adst, hw16);
    // 5-6) pos-BN stats
    k_pos_stats<<<1024, 256, 0, stream>>>(pos, src, pw1, pb1, p_pos);
    k_reduce_bn<<<1, 1024, 0, stream>>>(p_pos, 1024, 4, 3, 1.f / E_, pbg, pbb, ss_pos);
    // 7-8) attn_bn1 stats
    k_abn1_stats<<<2048, 256, 0, stream>>>(pos, src, asrc16, buf_adst,
                                           pw1, pb1, ss_pos, pw2, pb2, p_abn1);
    k_reduce_bn<<<1, 1024, 0, stream>>>(p_abn1, 2048, 64, 64, 1.f / E_, a1g, a1b, ss_a1);
    // 9-10) t1 + abn2 stats
    k_edge_t1<<<2048, 256, 0, stream>>>(pos, src, asrc16, buf_adst,
                                        pw1, pb1, ss_pos, pw2, pb2,
                                        ss_a1, aw1, ab1, buf_t1, p_abn2);
    k_reduce_bn<<<1, 1024, 0, stream>>>(p_abn2, 2048, 8, 8, 1.f / E_, a2g, a2b, ss_a2);
    // 11) softmax + weighted aggregate -> out [N,64]
    k_node_aggr<<<4096, 256, 0, stream>>>(pos, src, buf_t1, ss_a2, aw2, ab2,
                                          hw16, ss_pos, pw1, pb1, pw2, pb2, buf_out);
    // 12-13) bn2 stats
    k_colstats<<<256, 256, 0, stream>>>(buf_out, p_bn2);
    k_reduce_bn<<<1, 1024, 0, stream>>>(p_bn2, 256, 64, 64, 1.f / N_, bn2g, bn2b, ss_bn2);
    // 14) y3 = relu(bn2(out)) @ W_out^T
    k_gemm_tile<<<1024, 256, 0, stream>>>(buf_out, W_out, nullptr, ss_bn2, buf_y);
    // 15-16) bn3 stats
    k_colstats<<<256, 256, 0, stream>>>(buf_y, p_bn3);
    k_reduce_bn<<<1, 1024, 0, stream>>>(p_bn3, 256, 64, 64, 1.f / N_, bn3g, bn3b, ss_bn3);
    // 17) out = relu(bn3(y3) + x)
    k_final<<<(N_ * C_ / 4) / 256, 256, 0, stream>>>(buf_y, ss_bn3, x, outp);

    (void)in_sizes; (void)n_in; (void)out_size; (void)ws_size;
}